// Round 11
// baseline (509.231 us; speedup 1.0000x reference)
//
#include <hip/hip_runtime.h>
#include <math.h>

#define BB 256
#define NN 262144
#define DD 128
#define KK 4096
#define CAP 8192
#define NOUT (BB * (KK + 1))
#define THETA0 0.172f

#define RB 16            // rows per block
#define CB 1024          // cols per block
#define BK 8             // d's per staged chunk
#define NCH (DD / BK)    // 16 chunks
#define NRBLK (BB / RB)  // 16 row-blocks
#define NCSL (NN / CB)   // 256 col-slices
#define HSL (NCSL / 2)   // slices per variant (A/B split)
#define SLOTS 56         // per-row stash slots per block
#define PAD 32           // cnt stride in dwords -> 128 B per counter
// v1 LDS: Bs[2][BK][CB] (64K) + As[DD][RB] (8K) + stash + ctrs
#define SMEM1 ((2 * BK * CB + DD * RB) * 4 + RB * SLOTS * 8 + 3 * RB * 4)
// v2 LDS: Bs only + stash + ctrs (A comes from SGPRs)
#define SMEM2 ((2 * BK * CB) * 4 + RB * SLOTS * 8 + 3 * RB * 4)

typedef float v4f __attribute__((ext_vector_type(4)));

// ---------------- zero the per-row candidate counters (padded) ----------------
__global__ __launch_bounds__(256) void k_zero(unsigned* __restrict__ cnt) {
  for (int i = threadIdx.x; i < BB * PAD; i += 256) cnt[i] = 0u;
}

// ---- build At2[rowblk][d][16]: 64B-contiguous A-fragment per (rowblk,d) ----
__global__ __launch_bounds__(256) void k_tr2(const float* __restrict__ anchor,
                                             float* __restrict__ At2) {
  const int i = blockIdx.x * 256 + threadIdx.x;   // 32768
  const int r = i & 15, d = (i >> 4) & (DD - 1), rb = i >> 11;
  At2[i] = anchor[(size_t)(rb * RB + r) * DD + d];
}

// ================= shared pieces for both score variants =================
#define SCORE_PROLOGUE(EXTRA_LDS)                                            \
  extern __shared__ float smem[];                                            \
  float* Bs = smem; /* [2][BK][CB] */                                        \
  unsigned long long* stash =                                                \
      (unsigned long long*)(smem + 2 * BK * CB + (EXTRA_LDS));               \
  unsigned* lcnt = (unsigned*)(stash + RB * SLOTS);                          \
  unsigned* lbase = lcnt + RB;                                               \
  unsigned* lm = lbase + RB;                                                 \
  const int tid = threadIdx.x;                                               \
  const int wave = tid >> 6;                                                 \
  const int lane = tid & 63;                                                 \
  const int bid = blockIdx.x;                                                \
  const int xcd = bid & 7;                                                   \
  const int u = bid >> 3;                                                    \
  const int rowblk = u & (NRBLK - 1);                                        \
  const int sgrp = u >> 4;                                                   \
  const int rowbase = rowblk * RB;                                           \
  const int cb = (slice_base + sgrp * 8 + xcd) * CB;                         \
  if (tid < RB) lcnt[tid] = 0u;

#define STAGE_CHUNK(SLOT, D0)                                                \
  for (int t = wave; t < BK * 4; t += 4) {                                   \
    const int d = t >> 2, q = t & 3;                                         \
    const float* gsrc = bank + (size_t)((D0) + d) * NN + cb + q * 256 + lane * 4; \
    __builtin_amdgcn_global_load_lds(                                        \
        (const __attribute__((address_space(1))) void*)gsrc,                 \
        (__attribute__((address_space(3))) void*)                            \
            &Bs[((size_t)(SLOT)*BK + d) * CB + q * 256],                     \
        16, 0, 0);                                                           \
  }

#define SCORE_EPILOGUE                                                       \
  const float tv = thr[0];                                                   \
  _Pragma("unroll") for (int r = 0; r < RB; ++r) {                           \
    _Pragma("unroll") for (int c = 0; c < 4; ++c) {                          \
      const float s = acc[r * 4 + c];                                        \
      if (s >= THETA0 && s < tv) {                                           \
        const unsigned col = (unsigned)(cb + tid * 4 + c);                   \
        const unsigned long long key =                                       \
            ((unsigned long long)__float_as_uint(s) << 32) |                 \
            (unsigned long long)(0xFFFFFFFFu - col);                         \
        const unsigned lpos = atomicAdd(&lcnt[r], 1u);                       \
        if (lpos < SLOTS) {                                                  \
          stash[r * SLOTS + lpos] = key;                                     \
        } else {                                                             \
          const unsigned gpos =                                              \
              atomicAdd(&cnt[(size_t)(rowbase + r) * PAD], 1u);              \
          if (gpos < CAP) cand[(size_t)(rowbase + r) * CAP + gpos] = key;    \
        }                                                                    \
      }                                                                      \
    }                                                                        \
  }                                                                          \
  __syncthreads();                                                           \
  if (tid < RB) {                                                            \
    const unsigned m = min(lcnt[tid], (unsigned)SLOTS);                      \
    lm[tid] = m;                                                             \
    lbase[tid] = atomicAdd(&cnt[(size_t)(rowbase + tid) * PAD], m);          \
  }                                                                          \
  __syncthreads();                                                           \
  for (int i = tid; i < RB * SLOTS; i += 256) {                              \
    const int r = i / SLOTS, j = i - r * SLOTS;                              \
    if ((unsigned)j < lm[r]) {                                               \
      const unsigned pos = lbase[r] + (unsigned)j;                           \
      if (pos < CAP) cand[(size_t)(rowbase + r) * CAP + pos] = stash[i];     \
    }                                                                        \
  }

// ---------------- V1 (control = round 10): A via LDS ds_read_b128 ----------
__global__ __launch_bounds__(256, 2) void k_score_v1(
    const float* __restrict__ bank, const float* __restrict__ anchor,
    const float* __restrict__ thr, unsigned* __restrict__ cnt,
    unsigned long long* __restrict__ cand, int slice_base) {
  SCORE_PROLOGUE(DD * RB)
  float* As = smem + 2 * BK * CB;   // [DD][RB]

  for (int i = tid; i < DD * RB; i += 256) {
    const int d = i >> 4, r = i & (RB - 1);
    As[d * RB + r] = anchor[(size_t)(rowbase + r) * DD + d];
  }
  STAGE_CHUNK(0, 0)
  __syncthreads();

  float acc[64];
#pragma unroll
  for (int i = 0; i < 64; ++i) acc[i] = 0.f;

  for (int ch = 0; ch < NCH; ++ch) {
    const int cur = ch & 1;
    if (ch + 1 < NCH) { STAGE_CHUNK(cur ^ 1, (ch + 1) * BK) }

    const float* __restrict__ Bc = &Bs[(size_t)cur * BK * CB + tid * 4];
    const int d0 = ch * BK;
#pragma unroll
    for (int dd = 0; dd < BK; ++dd) {
      const float4 bv = *reinterpret_cast<const float4*>(&Bc[dd * CB]);
      const int d = d0 + dd;
#define FMA_ROW(R, AV)                                      \
      acc[(R) * 4 + 0] = fmaf(AV, bv.x, acc[(R) * 4 + 0]);  \
      acc[(R) * 4 + 1] = fmaf(AV, bv.y, acc[(R) * 4 + 1]);  \
      acc[(R) * 4 + 2] = fmaf(AV, bv.z, acc[(R) * 4 + 2]);  \
      acc[(R) * 4 + 3] = fmaf(AV, bv.w, acc[(R) * 4 + 3]);
#pragma unroll
      for (int j = 0; j < 4; ++j) {
        const float4 a = *reinterpret_cast<const float4*>(&As[d * RB + 4 * j]);
        FMA_ROW(4 * j + 0, a.x)
        FMA_ROW(4 * j + 1, a.y)
        FMA_ROW(4 * j + 2, a.z)
        FMA_ROW(4 * j + 3, a.w)
      }
#undef FMA_ROW
    }
    __syncthreads();
  }
  SCORE_EPILOGUE
}

// ---------------- V2: A via SGPR s_load (addrspace(4), uniform addr) --------
// At2[rowblk][d][16] is 64B-contiguous per (rowblk,d); address depends only on
// blockIdx + loop counter -> wave-uniform -> s_load_dwordx16 on the scalar
// pipe. LDS traffic per wave-d: ONE ds_read_b128 (B). FMA: v_fmac(vacc,s_a,v_b).
__global__ __launch_bounds__(256, 2) void k_score_v2(
    const float* __restrict__ bank, const float* __restrict__ At2,
    const float* __restrict__ thr, unsigned* __restrict__ cnt,
    unsigned long long* __restrict__ cand, int slice_base) {
  SCORE_PROLOGUE(0)

  const v4f __attribute__((address_space(4)))* Ac =
      (const v4f __attribute__((address_space(4)))*)(At2 +
                                                     (size_t)rowblk * DD * RB);

  STAGE_CHUNK(0, 0)
  __syncthreads();

  float acc[64];
#pragma unroll
  for (int i = 0; i < 64; ++i) acc[i] = 0.f;

  for (int ch = 0; ch < NCH; ++ch) {
    const int cur = ch & 1;
    if (ch + 1 < NCH) { STAGE_CHUNK(cur ^ 1, (ch + 1) * BK) }

    const float* __restrict__ Bc = &Bs[(size_t)cur * BK * CB + tid * 4];
    const int d0 = ch * BK;
#pragma unroll
    for (int dd = 0; dd < BK; ++dd) {
      const float4 bv = *reinterpret_cast<const float4*>(&Bc[dd * CB]);
      const int d = d0 + dd;
      const v4f a0 = Ac[d * 4 + 0];
      const v4f a1 = Ac[d * 4 + 1];
      const v4f a2 = Ac[d * 4 + 2];
      const v4f a3 = Ac[d * 4 + 3];
#define FMA_ROW(R, AV)                                      \
      acc[(R) * 4 + 0] = fmaf(AV, bv.x, acc[(R) * 4 + 0]);  \
      acc[(R) * 4 + 1] = fmaf(AV, bv.y, acc[(R) * 4 + 1]);  \
      acc[(R) * 4 + 2] = fmaf(AV, bv.z, acc[(R) * 4 + 2]);  \
      acc[(R) * 4 + 3] = fmaf(AV, bv.w, acc[(R) * 4 + 3]);
      FMA_ROW(0, a0.x) FMA_ROW(1, a0.y) FMA_ROW(2, a0.z) FMA_ROW(3, a0.w)
      FMA_ROW(4, a1.x) FMA_ROW(5, a1.y) FMA_ROW(6, a1.z) FMA_ROW(7, a1.w)
      FMA_ROW(8, a2.x) FMA_ROW(9, a2.y) FMA_ROW(10, a2.z) FMA_ROW(11, a2.w)
      FMA_ROW(12, a3.x) FMA_ROW(13, a3.y) FMA_ROW(14, a3.z) FMA_ROW(15, a3.w)
#undef FMA_ROW
    }
    __syncthreads();
  }
  SCORE_EPILOGUE
}

// ---------------- per-row bitonic sort of u64 keys (descending) ----------------
__global__ void k_sort(const unsigned* __restrict__ cnt,
                       const unsigned long long* __restrict__ cand,
                       unsigned* __restrict__ neg) {
  extern __shared__ unsigned long long sk[];
  const int b = blockIdx.x;
  unsigned m = cnt[(size_t)b * PAD];
  if (m > CAP) m = CAP;

  for (int i = threadIdx.x; i < CAP; i += (int)blockDim.x)
    sk[i] = (i < (int)m) ? cand[(size_t)b * CAP + i] : 0ULL;  // 0 sorts last
  __syncthreads();

  for (int k = 2; k <= CAP; k <<= 1) {
    for (int j = k >> 1; j > 0; j >>= 1) {
      for (int i = threadIdx.x; i < CAP / 2; i += (int)blockDim.x) {
        int t = i & (j - 1);
        int p = ((i - t) << 1) + t;
        int q = p + j;
        bool up = ((p & k) == 0);
        unsigned long long a = sk[p], c = sk[q];
        bool sw = up ? (a < c) : (a > c);
        if (sw) { sk[p] = c; sk[q] = a; }
      }
      __syncthreads();
    }
  }

  for (int i = threadIdx.x; i < KK; i += (int)blockDim.x) {
    unsigned idx = 0xFFFFFFFFu - (unsigned)(sk[i] & 0xFFFFFFFFull);
    neg[(size_t)b * KK + i] = (sk[i] == 0ULL) ? 0u : idx;
  }
}

// ---------------- contrast: out = exp(dot/T), block partial sums for Z ----------
__global__ __launch_bounds__(256) void k_contrast(
    const float* __restrict__ anchor, const float* __restrict__ pair,
    const float* __restrict__ bank, const unsigned* __restrict__ neg,
    float* __restrict__ out, double* __restrict__ zpart) {
  __shared__ __align__(16) float As[DD];
  __shared__ double wsum[4];
  const int bid = blockIdx.x;
  double myv;
  if (bid < BB * (KK / 256)) {           // 4096 negative blocks
    const int b = bid >> 4;
    const int k = ((bid & 15) << 8) + threadIdx.x;
    if (threadIdx.x < DD) As[threadIdx.x] = anchor[(size_t)b * DD + threadIdx.x];
    __syncthreads();
    const unsigned idx = neg[(size_t)b * KK + k];
    const float4* __restrict__ rp = (const float4*)(bank + (size_t)idx * DD);
    const float4* __restrict__ apv = (const float4*)As;
    float s = 0.f;
#pragma unroll
    for (int q = 0; q < DD / 4; ++q) {
      float4 rv = rp[q], av = apv[q];
      s = fmaf(rv.x, av.x, s);
      s = fmaf(rv.y, av.y, s);
      s = fmaf(rv.z, av.z, s);
      s = fmaf(rv.w, av.w, s);
    }
    float e = expf(s * (1.0f / 0.07f));
    out[(size_t)b * (KK + 1) + 1 + k] = e;
    myv = (double)e;
  } else {                               // positive slot: out[b][0]
    const int b = threadIdx.x;
    const float* __restrict__ apr = anchor + (size_t)b * DD;
    const float* __restrict__ ppr = pair + (size_t)b * DD;
    float s = 0.f;
#pragma unroll
    for (int q = 0; q < DD; ++q) s = fmaf(apr[q], ppr[q], s);
    float e = expf(s * (1.0f / 0.07f));
    out[(size_t)b * (KK + 1)] = e;
    myv = (double)e;
  }
  for (int off = 32; off > 0; off >>= 1) myv += __shfl_down(myv, off, 64);
  if ((threadIdx.x & 63) == 0) wsum[threadIdx.x >> 6] = myv;
  __syncthreads();
  if (threadIdx.x == 0) zpart[bid] = (wsum[0] + wsum[1]) + (wsum[2] + wsum[3]);
}

// ---------------- Z reduction (deterministic) ----------------
__global__ void k_zreduce(const double* __restrict__ zpart, double* __restrict__ invZ) {
  __shared__ double w[16];
  double v = 0.0;
  for (int i = threadIdx.x; i < BB * (KK / 256) + 1; i += 1024) v += zpart[i];
  for (int off = 32; off > 0; off >>= 1) v += __shfl_down(v, off, 64);
  if ((threadIdx.x & 63) == 0) w[threadIdx.x >> 6] = v;
  __syncthreads();
  if (threadIdx.x == 0) {
    double t = 0.0;
    for (int q = 0; q < 16; ++q) t += w[q];
    double Z = t / ((double)BB * (double)(KK + 1)) * (double)NN;
    invZ[0] = 1.0 / Z;
  }
}

// ---------------- final scale ----------------
__global__ void k_scale(float* __restrict__ out, const double* __restrict__ invZ) {
  double iz = invZ[0];
  int i = blockIdx.x * 512 + threadIdx.x;
  if (i < NOUT) out[i] = (float)((double)out[i] * iz);
}

extern "C" void kernel_launch(void* const* d_in, const int* in_sizes, int n_in,
                              void* d_out, int out_size, void* d_ws, size_t ws_size,
                              hipStream_t stream) {
  const float* anchor = (const float*)d_in[0];
  const float* pair   = (const float*)d_in[1];
  const float* bank   = (const float*)d_in[2];
  const float* thr    = (const float*)d_in[4];
  float* out = (float*)d_out;

  char* w = (char*)d_ws;
  unsigned* cnt = (unsigned*)(w);                                   // 32 KiB (padded)
  unsigned long long* cand = (unsigned long long*)(w + BB * PAD * 4);  // 16 MiB
  unsigned* neg = (unsigned*)(w + BB * PAD * 4 + (size_t)BB * CAP * 8);  // 4 MiB
  double* zpart = (double*)(w + BB * PAD * 4 + (size_t)BB * CAP * 8 + (size_t)BB * KK * 4);
  double* invZ  = (double*)((char*)zpart + (size_t)(BB * (KK / 256) + 1) * 8);
  float*  At2   = (float*)((char*)invZ + 256);                      // 128 KiB

  k_zero<<<1, 256, 0, stream>>>(cnt);
  k_tr2<<<BB * DD / 256, 256, 0, stream>>>(anchor, At2);
  (void)hipFuncSetAttribute((const void*)k_score_v1,
                            hipFuncAttributeMaxDynamicSharedMemorySize, SMEM1);
  (void)hipFuncSetAttribute((const void*)k_score_v2,
                            hipFuncAttributeMaxDynamicSharedMemorySize, SMEM2);
  // A/B: v1 = slices [0,128), v2 = slices [128,256) -- same launch, two rows
  // in the profile give a direct within-probe comparison.
  k_score_v1<<<NRBLK * HSL, 256, SMEM1, stream>>>(bank, anchor, thr, cnt, cand, 0);
  k_score_v2<<<NRBLK * HSL, 256, SMEM2, stream>>>(bank, At2, thr, cnt, cand, HSL);
  (void)hipFuncSetAttribute((const void*)k_sort,
                            hipFuncAttributeMaxDynamicSharedMemorySize, CAP * 8);
  k_sort<<<BB, 1024, CAP * 8, stream>>>(cnt, cand, neg);
  k_contrast<<<BB * (KK / 256) + 1, 256, 0, stream>>>(anchor, pair, bank, neg, out, zpart);
  k_zreduce<<<1, 1024, 0, stream>>>(zpart, invZ);
  k_scale<<<(NOUT + 511) / 512, 512, 0, stream>>>(out, invZ);
}

// Round 12
// 502.271 us; speedup vs baseline: 1.0139x; 1.0139x over previous
//
#include <hip/hip_runtime.h>
#include <math.h>

#define BB 256
#define NN 262144
#define DD 128
#define KK 4096
#define CAP 8192
#define NOUT (BB * (KK + 1))
#define THETA0 0.172f

#define RB 16            // rows per block
#define CB 1024          // cols per block
#define BK 8             // d's per staged chunk
#define NCH (DD / BK)    // 16 chunks
#define NRBLK (BB / RB)  // 16 row-blocks
#define NCSL (NN / CB)   // 256 col-slices
#define HSL (NCSL / 2)   // slices per variant (A/B split)
#define SLOTS 56         // per-row stash slots per block
#define PAD 32           // cnt stride in dwords -> 128 B per counter
// v1 LDS: Bs[2][BK][CB] (64K) + As[DD][16] (8K) + stash + ctrs
#define SMEM1 ((2 * BK * CB + DD * 16) * 4 + RB * SLOTS * 8 + 3 * RB * 4)
// v2 LDS: Bs only + stash + ctrs (A from global/L1)
#define SMEM2 ((2 * BK * CB) * 4 + RB * SLOTS * 8 + 3 * RB * 4)

typedef float f2 __attribute__((ext_vector_type(2)));

static __device__ __forceinline__ f2 pkfma(f2 a, f2 b, f2 c) {
  return __builtin_elementwise_fma(a, b, c);   // v_pk_fma_f32: 2 independent IEEE FMAs
}

// ---------------- zero the per-row candidate counters (padded) ----------------
__global__ __launch_bounds__(256) void k_zero(unsigned* __restrict__ cnt) {
  for (int i = threadIdx.x; i < BB * PAD; i += 256) cnt[i] = 0u;
}

// ---- build At2[rowblk][d][16]: 64B-contiguous A-fragment per (rowblk,d) ----
__global__ __launch_bounds__(256) void k_tr2(const float* __restrict__ anchor,
                                             float* __restrict__ At2) {
  const int i = blockIdx.x * 256 + threadIdx.x;   // 32768
  const int r = i & 15, d = (i >> 4) & (DD - 1), rb = i >> 11;
  At2[i] = anchor[(size_t)(rb * RB + r) * DD + d];
}

// ================= shared pieces for both score variants =================
// thread tile: 8 rows x 8 cols. waves 0-1 -> rows 0-7, waves 2-3 -> rows 8-15.
// l = tid&127 covers 1024 cols as two groups: 4l..4l+3 and 512+4l..+3.
#define SCORE_PROLOGUE(EXTRA_LDS)                                            \
  extern __shared__ float smem[];                                            \
  float* Bs = smem; /* [2][BK][CB] */                                        \
  unsigned long long* stash =                                                \
      (unsigned long long*)(smem + 2 * BK * CB + (EXTRA_LDS));               \
  unsigned* lcnt = (unsigned*)(stash + RB * SLOTS);                          \
  unsigned* lbase = lcnt + RB;                                               \
  unsigned* lm = lbase + RB;                                                 \
  const int tid = threadIdx.x;                                               \
  const int wave = tid >> 6;                                                 \
  const int lane = tid & 63;                                                 \
  const int l = tid & 127;                                                   \
  const int rh = tid >> 7;                                                   \
  const int bid = blockIdx.x;                                                \
  const int xcd = bid & 7;                                                   \
  const int u = bid >> 3;                                                    \
  const int rowblk = u & (NRBLK - 1);                                        \
  const int sgrp = u >> 4;                                                   \
  const int rowbase = rowblk * RB;                                           \
  const int cb = (slice_base + sgrp * 8 + xcd) * CB;                         \
  if (tid < RB) lcnt[tid] = 0u;

#define STAGE_CHUNK(SLOT, D0)                                                \
  for (int t = wave; t < BK * 4; t += 4) {                                   \
    const int d = t >> 2, q = t & 3;                                         \
    const float* gsrc = bank + (size_t)((D0) + d) * NN + cb + q * 256 + lane * 4; \
    __builtin_amdgcn_global_load_lds(                                        \
        (const __attribute__((address_space(1))) void*)gsrc,                 \
        (__attribute__((address_space(3))) void*)                            \
            &Bs[((size_t)(SLOT)*BK + d) * CB + q * 256],                     \
        16, 0, 0);                                                           \
  }

// APPEND(s, col) : candidate append via LDS stash + block-level reservation
#define APPEND(SVAL, COLV, ROWV)                                             \
  if ((SVAL) >= THETA0 && (SVAL) < tv) {                                     \
    const unsigned long long key =                                           \
        ((unsigned long long)__float_as_uint(SVAL) << 32) |                  \
        (unsigned long long)(0xFFFFFFFFu - (unsigned)(COLV));                \
    const unsigned lpos = atomicAdd(&lcnt[ROWV], 1u);                        \
    if (lpos < SLOTS) {                                                      \
      stash[(ROWV)*SLOTS + lpos] = key;                                      \
    } else {                                                                 \
      const unsigned gpos =                                                  \
          atomicAdd(&cnt[(size_t)(rowbase + (ROWV)) * PAD], 1u);             \
      if (gpos < CAP) cand[(size_t)(rowbase + (ROWV)) * CAP + gpos] = key;   \
    }                                                                        \
  }

#define SCORE_FLUSH                                                          \
  __syncthreads();                                                           \
  if (tid < RB) {                                                            \
    const unsigned m = min(lcnt[tid], (unsigned)SLOTS);                      \
    lm[tid] = m;                                                             \
    lbase[tid] = atomicAdd(&cnt[(size_t)(rowbase + tid) * PAD], m);          \
  }                                                                          \
  __syncthreads();                                                           \
  for (int i = tid; i < RB * SLOTS; i += 256) {                              \
    const int r = i / SLOTS, j = i - r * SLOTS;                              \
    if ((unsigned)j < lm[r]) {                                               \
      const unsigned pos = lbase[r] + (unsigned)j;                           \
      if (pos < CAP) cand[(size_t)(rowbase + r) * CAP + pos] = stash[i];     \
    }                                                                        \
  }

// ---------------- V1 (control): 8x8 tile, A via LDS ds_read_b128 ----------
__global__ __launch_bounds__(256, 2) void k_score_v1(
    const float* __restrict__ bank, const float* __restrict__ anchor,
    const float* __restrict__ thr, unsigned* __restrict__ cnt,
    unsigned long long* __restrict__ cand, int slice_base) {
  SCORE_PROLOGUE(DD * 16)
  float* As = smem + 2 * BK * CB;   // [DD][16]

  for (int i = tid; i < DD * 16; i += 256) {
    const int d = i >> 4, r = i & 15;
    As[d * 16 + r] = anchor[(size_t)(rowbase + r) * DD + d];
  }
  STAGE_CHUNK(0, 0)
  __syncthreads();

  float acc[64];   // [r(8)][c(8)]: c 0-3 = cols 4l.., c 4-7 = cols 512+4l..
#pragma unroll
  for (int i = 0; i < 64; ++i) acc[i] = 0.f;

  const float4* __restrict__ As4 = (const float4*)As;

  for (int ch = 0; ch < NCH; ++ch) {
    const int cur = ch & 1;
    if (ch + 1 < NCH) { STAGE_CHUNK(cur ^ 1, (ch + 1) * BK) }

    const float* __restrict__ Bc = &Bs[(size_t)cur * BK * CB];
    const int d0 = ch * BK;
#pragma unroll
    for (int dd = 0; dd < BK; ++dd) {
      const int d = d0 + dd;
      const float4 a0 = As4[d * 4 + rh * 2];       // rows rh*8 .. +3
      const float4 a1 = As4[d * 4 + rh * 2 + 1];   // rows rh*8+4 .. +7
      const float4 bx = *(const float4*)&Bc[dd * CB + 4 * l];
      const float4 by = *(const float4*)&Bc[dd * CB + 4 * l + 512];
#define FMA_ROW(R, AV)                                  \
      acc[(R)*8 + 0] = fmaf(AV, bx.x, acc[(R)*8 + 0]); \
      acc[(R)*8 + 1] = fmaf(AV, bx.y, acc[(R)*8 + 1]); \
      acc[(R)*8 + 2] = fmaf(AV, bx.z, acc[(R)*8 + 2]); \
      acc[(R)*8 + 3] = fmaf(AV, bx.w, acc[(R)*8 + 3]); \
      acc[(R)*8 + 4] = fmaf(AV, by.x, acc[(R)*8 + 4]); \
      acc[(R)*8 + 5] = fmaf(AV, by.y, acc[(R)*8 + 5]); \
      acc[(R)*8 + 6] = fmaf(AV, by.z, acc[(R)*8 + 6]); \
      acc[(R)*8 + 7] = fmaf(AV, by.w, acc[(R)*8 + 7]);
      FMA_ROW(0, a0.x) FMA_ROW(1, a0.y) FMA_ROW(2, a0.z) FMA_ROW(3, a0.w)
      FMA_ROW(4, a1.x) FMA_ROW(5, a1.y) FMA_ROW(6, a1.z) FMA_ROW(7, a1.w)
#undef FMA_ROW
    }
    __syncthreads();
  }

  const float tv = thr[0];
#pragma unroll
  for (int r = 0; r < 8; ++r) {
    const int brow = rh * 8 + r;
#pragma unroll
    for (int c = 0; c < 8; ++c) {
      const float s = acc[r * 8 + c];
      const int col = cb + (c < 4 ? 4 * l + c : 512 + 4 * l + (c - 4));
      APPEND(s, col, brow)
    }
  }
  SCORE_FLUSH
}

// ---------------- V2: 8x8 tile, A from global (L1-resident), pk FMA ---------
__global__ __launch_bounds__(256, 2) void k_score_v2(
    const float* __restrict__ bank, const float* __restrict__ At2,
    const float* __restrict__ thr, unsigned* __restrict__ cnt,
    unsigned long long* __restrict__ cand, int slice_base) {
  SCORE_PROLOGUE(0)

  const float4* __restrict__ Ac4 =
      (const float4*)(At2 + (size_t)rowblk * DD * 16);

  STAGE_CHUNK(0, 0)
  __syncthreads();

  f2 acc2[32];   // [r(8)][q(4)]: q0,q1 = cols 4l+{0,1},{2,3}; q2,q3 = +512
#pragma unroll
  for (int i = 0; i < 32; ++i) acc2[i] = (f2){0.f, 0.f};

  for (int ch = 0; ch < NCH; ++ch) {
    const int cur = ch & 1;
    if (ch + 1 < NCH) { STAGE_CHUNK(cur ^ 1, (ch + 1) * BK) }

    const float* __restrict__ Bc = &Bs[(size_t)cur * BK * CB];
    const int d0 = ch * BK;
#pragma unroll 2
    for (int dd = 0; dd < BK; ++dd) {
      const int d = d0 + dd;
      const float4 a0 = Ac4[d * 4 + rh * 2];       // uniform -> L1 broadcast
      const float4 a1 = Ac4[d * 4 + rh * 2 + 1];
      const float4 bx = *(const float4*)&Bc[dd * CB + 4 * l];
      const float4 by = *(const float4*)&Bc[dd * CB + 4 * l + 512];
      const f2 b0 = {bx.x, bx.y}, b1 = {bx.z, bx.w};
      const f2 b2 = {by.x, by.y}, b3 = {by.z, by.w};
#define FMA_ROW(R, AV)                                          \
      {                                                         \
        const f2 a2 = {AV, AV};                                 \
        acc2[(R)*4 + 0] = pkfma(a2, b0, acc2[(R)*4 + 0]);       \
        acc2[(R)*4 + 1] = pkfma(a2, b1, acc2[(R)*4 + 1]);       \
        acc2[(R)*4 + 2] = pkfma(a2, b2, acc2[(R)*4 + 2]);       \
        acc2[(R)*4 + 3] = pkfma(a2, b3, acc2[(R)*4 + 3]);       \
      }
      FMA_ROW(0, a0.x) FMA_ROW(1, a0.y) FMA_ROW(2, a0.z) FMA_ROW(3, a0.w)
      FMA_ROW(4, a1.x) FMA_ROW(5, a1.y) FMA_ROW(6, a1.z) FMA_ROW(7, a1.w)
#undef FMA_ROW
    }
    __syncthreads();
  }

  const float tv = thr[0];
#pragma unroll
  for (int r = 0; r < 8; ++r) {
    const int brow = rh * 8 + r;
#pragma unroll
    for (int q = 0; q < 4; ++q) {
      const int colb = cb + (q < 2 ? 4 * l + 2 * q : 512 + 4 * l + 2 * (q - 2));
      const float s0 = acc2[r * 4 + q].x;
      const float s1 = acc2[r * 4 + q].y;
      APPEND(s0, colb, brow)
      APPEND(s1, colb + 1, brow)
    }
  }
  SCORE_FLUSH
}

// ---------------- per-row bitonic sort of u64 keys (descending) ----------------
__global__ void k_sort(const unsigned* __restrict__ cnt,
                       const unsigned long long* __restrict__ cand,
                       unsigned* __restrict__ neg) {
  extern __shared__ unsigned long long sk[];
  const int b = blockIdx.x;
  unsigned m = cnt[(size_t)b * PAD];
  if (m > CAP) m = CAP;

  for (int i = threadIdx.x; i < CAP; i += (int)blockDim.x)
    sk[i] = (i < (int)m) ? cand[(size_t)b * CAP + i] : 0ULL;  // 0 sorts last
  __syncthreads();

  for (int k = 2; k <= CAP; k <<= 1) {
    for (int j = k >> 1; j > 0; j >>= 1) {
      for (int i = threadIdx.x; i < CAP / 2; i += (int)blockDim.x) {
        int t = i & (j - 1);
        int p = ((i - t) << 1) + t;
        int q = p + j;
        bool up = ((p & k) == 0);
        unsigned long long a = sk[p], c = sk[q];
        bool sw = up ? (a < c) : (a > c);
        if (sw) { sk[p] = c; sk[q] = a; }
      }
      __syncthreads();
    }
  }

  for (int i = threadIdx.x; i < KK; i += (int)blockDim.x) {
    unsigned idx = 0xFFFFFFFFu - (unsigned)(sk[i] & 0xFFFFFFFFull);
    neg[(size_t)b * KK + i] = (sk[i] == 0ULL) ? 0u : idx;
  }
}

// ---------------- contrast: out = exp(dot/T), block partial sums for Z ----------
__global__ __launch_bounds__(256) void k_contrast(
    const float* __restrict__ anchor, const float* __restrict__ pair,
    const float* __restrict__ bank, const unsigned* __restrict__ neg,
    float* __restrict__ out, double* __restrict__ zpart) {
  __shared__ __align__(16) float As[DD];
  __shared__ double wsum[4];
  const int bid = blockIdx.x;
  double myv;
  if (bid < BB * (KK / 256)) {           // 4096 negative blocks
    const int b = bid >> 4;
    const int k = ((bid & 15) << 8) + threadIdx.x;
    if (threadIdx.x < DD) As[threadIdx.x] = anchor[(size_t)b * DD + threadIdx.x];
    __syncthreads();
    const unsigned idx = neg[(size_t)b * KK + k];
    const float4* __restrict__ rp = (const float4*)(bank + (size_t)idx * DD);
    const float4* __restrict__ apv = (const float4*)As;
    float s = 0.f;
#pragma unroll
    for (int q = 0; q < DD / 4; ++q) {
      float4 rv = rp[q], av = apv[q];
      s = fmaf(rv.x, av.x, s);
      s = fmaf(rv.y, av.y, s);
      s = fmaf(rv.z, av.z, s);
      s = fmaf(rv.w, av.w, s);
    }
    float e = expf(s * (1.0f / 0.07f));
    out[(size_t)b * (KK + 1) + 1 + k] = e;
    myv = (double)e;
  } else {                               // positive slot: out[b][0]
    const int b = threadIdx.x;
    const float* __restrict__ apr = anchor + (size_t)b * DD;
    const float* __restrict__ ppr = pair + (size_t)b * DD;
    float s = 0.f;
#pragma unroll
    for (int q = 0; q < DD; ++q) s = fmaf(apr[q], ppr[q], s);
    float e = expf(s * (1.0f / 0.07f));
    out[(size_t)b * (KK + 1)] = e;
    myv = (double)e;
  }
  for (int off = 32; off > 0; off >>= 1) myv += __shfl_down(myv, off, 64);
  if ((threadIdx.x & 63) == 0) wsum[threadIdx.x >> 6] = myv;
  __syncthreads();
  if (threadIdx.x == 0) zpart[bid] = (wsum[0] + wsum[1]) + (wsum[2] + wsum[3]);
}

// ---------------- Z reduction (deterministic) ----------------
__global__ void k_zreduce(const double* __restrict__ zpart, double* __restrict__ invZ) {
  __shared__ double w[16];
  double v = 0.0;
  for (int i = threadIdx.x; i < BB * (KK / 256) + 1; i += 1024) v += zpart[i];
  for (int off = 32; off > 0; off >>= 1) v += __shfl_down(v, off, 64);
  if ((threadIdx.x & 63) == 0) w[threadIdx.x >> 6] = v;
  __syncthreads();
  if (threadIdx.x == 0) {
    double t = 0.0;
    for (int q = 0; q < 16; ++q) t += w[q];
    double Z = t / ((double)BB * (double)(KK + 1)) * (double)NN;
    invZ[0] = 1.0 / Z;
  }
}

// ---------------- final scale ----------------
__global__ void k_scale(float* __restrict__ out, const double* __restrict__ invZ) {
  double iz = invZ[0];
  int i = blockIdx.x * 512 + threadIdx.x;
  if (i < NOUT) out[i] = (float)((double)out[i] * iz);
}

extern "C" void kernel_launch(void* const* d_in, const int* in_sizes, int n_in,
                              void* d_out, int out_size, void* d_ws, size_t ws_size,
                              hipStream_t stream) {
  const float* anchor = (const float*)d_in[0];
  const float* pair   = (const float*)d_in[1];
  const float* bank   = (const float*)d_in[2];
  const float* thr    = (const float*)d_in[4];
  float* out = (float*)d_out;

  char* w = (char*)d_ws;
  unsigned* cnt = (unsigned*)(w);                                   // 32 KiB (padded)
  unsigned long long* cand = (unsigned long long*)(w + BB * PAD * 4);  // 16 MiB
  unsigned* neg = (unsigned*)(w + BB * PAD * 4 + (size_t)BB * CAP * 8);  // 4 MiB
  double* zpart = (double*)(w + BB * PAD * 4 + (size_t)BB * CAP * 8 + (size_t)BB * KK * 4);
  double* invZ  = (double*)((char*)zpart + (size_t)(BB * (KK / 256) + 1) * 8);
  float*  At2   = (float*)((char*)invZ + 256);                      // 128 KiB

  k_zero<<<1, 256, 0, stream>>>(cnt);
  k_tr2<<<BB * DD / 256, 256, 0, stream>>>(anchor, At2);
  (void)hipFuncSetAttribute((const void*)k_score_v1,
                            hipFuncAttributeMaxDynamicSharedMemorySize, SMEM1);
  (void)hipFuncSetAttribute((const void*)k_score_v2,
                            hipFuncAttributeMaxDynamicSharedMemorySize, SMEM2);
  // A/B: v1 = slices [0,128), v2 = slices [128,256)
  k_score_v1<<<NRBLK * HSL, 256, SMEM1, stream>>>(bank, anchor, thr, cnt, cand, 0);
  k_score_v2<<<NRBLK * HSL, 256, SMEM2, stream>>>(bank, At2, thr, cnt, cand, HSL);
  (void)hipFuncSetAttribute((const void*)k_sort,
                            hipFuncAttributeMaxDynamicSharedMemorySize, CAP * 8);
  k_sort<<<BB, 1024, CAP * 8, stream>>>(cnt, cand, neg);
  k_contrast<<<BB * (KK / 256) + 1, 256, 0, stream>>>(anchor, pair, bank, neg, out, zpart);
  k_zreduce<<<1, 1024, 0, stream>>>(zpart, invZ);
  k_scale<<<(NOUT + 511) / 512, 512, 0, stream>>>(out, invZ);
}

// Round 13
// 455.763 us; speedup vs baseline: 1.1173x; 1.1020x over previous
//
#include <hip/hip_runtime.h>
#include <math.h>

#define BB 256
#define NN 262144
#define DD 128
#define KK 4096
#define CAP 8192
#define NOUT (BB * (KK + 1))
#define THETA0 0.172f

#define RB 16            // rows per block
#define CB 1024          // cols per block
#define NRBLK (BB / RB)  // 16 row-blocks
#define NCSL (NN / CB)   // 256 col-slices
#define HSL (NCSL / 2)   // slices per variant (A/B split)
#define SLOTS 56         // per-row stash slots per block
#define PAD 32           // cnt stride in dwords -> 128 B per counter
// LDS bytes for a given BK: Bs[2][BK][CB] + As[DD][16] + stash + ctrs
#define SMEM(BKv) ((2 * (BKv) * CB + DD * 16) * 4 + RB * SLOTS * 8 + 3 * RB * 4)

typedef float f2 __attribute__((ext_vector_type(2)));

static __device__ __forceinline__ f2 pkfma(f2 a, f2 b, f2 c) {
  return __builtin_elementwise_fma(a, b, c);   // v_pk_fma_f32: 2 independent IEEE FMAs
}

// ---------------- zero the per-row candidate counters (padded) ----------------
__global__ __launch_bounds__(256) void k_zero(unsigned* __restrict__ cnt) {
  for (int i = threadIdx.x; i < BB * PAD; i += 256) cnt[i] = 0u;
}

// ---------------- f32 score GEMM (bit-exact sgemm order) + threshold append ----
// scores[b][n] = sequential f32 FMA over d=0..127 of anchor[b][d]*bank_flat[d*NN+n]
// Structure = round-12 v1 (winner): 8 rows x 8 cols per thread, A via LDS
// uniform-address ds_read_b128 broadcast, B via global_load_lds 2-phase ring.
// NEW: (1) v_pk_fma_f32 (2 IEEE FMAs/instr, per-element d-ascending chain
// unchanged -> bit-exact; pk path proven on HW in r12-v2); (2) template BK:
// BK=8 -> 81KB LDS, 2 blocks/CU; BK=4 -> 48KB, 3 blocks/CU (A/B this round).
template <int BKv, int MINW>
__global__ __launch_bounds__(256, MINW) void k_score(
    const float* __restrict__ bank, const float* __restrict__ anchor,
    const float* __restrict__ thr, unsigned* __restrict__ cnt,
    unsigned long long* __restrict__ cand, int slice_base) {
  constexpr int NCHv = DD / BKv;
  extern __shared__ float smem[];
  float* Bs = smem;                                  // [2][BKv][CB]
  float* As = smem + 2 * BKv * CB;                   // [DD][16]
  unsigned long long* stash =
      (unsigned long long*)(smem + 2 * BKv * CB + DD * 16);  // [RB][SLOTS]
  unsigned* lcnt  = (unsigned*)(stash + RB * SLOTS);
  unsigned* lbase = lcnt + RB;
  unsigned* lm    = lbase + RB;

  const int tid = threadIdx.x;
  const int wave = tid >> 6;
  const int lane = tid & 63;
  const int l = tid & 127;       // col group: 4l..4l+3 and 512+4l..+3
  const int rh = tid >> 7;       // row half: rows rh*8 .. rh*8+7
  const int bid = blockIdx.x;
  const int xcd = bid & 7;
  const int u = bid >> 3;
  const int rowblk = u & (NRBLK - 1);
  const int sgrp = u >> 4;
  const int rowbase = rowblk * RB;
  const int cb = (slice_base + sgrp * 8 + xcd) * CB;

  if (tid < RB) lcnt[tid] = 0u;

  // ---- stage A once: As[d*16 + r] = anchor[(rowbase+r)*128 + d] ----
  for (int i = tid; i < DD * 16; i += 256) {
    const int d = i >> 4, r = i & 15;
    As[d * 16 + r] = anchor[(size_t)(rowbase + r) * DD + d];
  }

#define STAGE_CHUNK(SLOT, D0)                                                \
  for (int t = wave; t < BKv * 4; t += 4) {                                  \
    const int d = t >> 2, q = t & 3;                                         \
    const float* gsrc =                                                      \
        bank + (size_t)((D0) + d) * NN + cb + q * 256 + lane * 4;            \
    __builtin_amdgcn_global_load_lds(                                        \
        (const __attribute__((address_space(1))) void*)gsrc,                 \
        (__attribute__((address_space(3))) void*)                            \
            &Bs[((size_t)(SLOT)*BKv + d) * CB + q * 256],                    \
        16, 0, 0);                                                           \
  }

  STAGE_CHUNK(0, 0)
  __syncthreads();   // drains vmcnt(0) -> chunk 0 ready

  f2 acc2[32];   // [r(8)][q(4)]: q0,q1 = cols 4l+{0,1},{2,3}; q2,q3 = +512
#pragma unroll
  for (int i = 0; i < 32; ++i) acc2[i] = (f2){0.f, 0.f};

  const float4* __restrict__ As4 = (const float4*)As;

  for (int ch = 0; ch < NCHv; ++ch) {
    const int cur = ch & 1;
    if (ch + 1 < NCHv) { STAGE_CHUNK(cur ^ 1, (ch + 1) * BKv) }

    const float* __restrict__ Bc = &Bs[(size_t)cur * BKv * CB];
    const int d0 = ch * BKv;
#pragma unroll
    for (int dd = 0; dd < BKv; ++dd) {
      const int d = d0 + dd;
      const float4 a0 = As4[d * 4 + rh * 2];       // uniform addr -> broadcast
      const float4 a1 = As4[d * 4 + rh * 2 + 1];
      const float4 bx = *(const float4*)&Bc[dd * CB + 4 * l];
      const float4 by = *(const float4*)&Bc[dd * CB + 4 * l + 512];
      const f2 b0 = {bx.x, bx.y}, b1 = {bx.z, bx.w};
      const f2 b2 = {by.x, by.y}, b3 = {by.z, by.w};
#define FMA_ROW(R, AV)                                          \
      {                                                         \
        const f2 av2 = {AV, AV};                                \
        acc2[(R)*4 + 0] = pkfma(av2, b0, acc2[(R)*4 + 0]);      \
        acc2[(R)*4 + 1] = pkfma(av2, b1, acc2[(R)*4 + 1]);      \
        acc2[(R)*4 + 2] = pkfma(av2, b2, acc2[(R)*4 + 2]);      \
        acc2[(R)*4 + 3] = pkfma(av2, b3, acc2[(R)*4 + 3]);      \
      }
      FMA_ROW(0, a0.x) FMA_ROW(1, a0.y) FMA_ROW(2, a0.z) FMA_ROW(3, a0.w)
      FMA_ROW(4, a1.x) FMA_ROW(5, a1.y) FMA_ROW(6, a1.z) FMA_ROW(7, a1.w)
#undef FMA_ROW
    }
    __syncthreads();   // drains this iter's gll; ring safe
  }
#undef STAGE_CHUNK

  // ---- two-level threshold append ----
  const float tv = thr[0];   // ref masks scores >= thr to -2.0 -> never candidates
#pragma unroll
  for (int r = 0; r < 8; ++r) {
    const int brow = rh * 8 + r;
#pragma unroll
    for (int q = 0; q < 4; ++q) {
      const int colb = cb + (q < 2 ? 4 * l + 2 * q : 512 + 4 * l + 2 * (q - 2));
#pragma unroll
      for (int e = 0; e < 2; ++e) {
        const float s = (e == 0) ? acc2[r * 4 + q].x : acc2[r * 4 + q].y;
        if (s >= THETA0 && s < tv) {
          // key: desc by f32 score bits (all candidates > 0), tie -> asc idx
          const unsigned long long key =
              ((unsigned long long)__float_as_uint(s) << 32) |
              (unsigned long long)(0xFFFFFFFFu - (unsigned)(colb + e));
          const unsigned lpos = atomicAdd(&lcnt[brow], 1u);
          if (lpos < SLOTS) {
            stash[brow * SLOTS + lpos] = key;
          } else {  // overflow fallback (statistically never; correctness-safe)
            const unsigned gpos =
                atomicAdd(&cnt[(size_t)(rowbase + brow) * PAD], 1u);
            if (gpos < CAP) cand[(size_t)(rowbase + brow) * CAP + gpos] = key;
          }
        }
      }
    }
  }
  __syncthreads();

  if (tid < RB) {
    const unsigned m = min(lcnt[tid], (unsigned)SLOTS);
    lm[tid] = m;
    lbase[tid] = atomicAdd(&cnt[(size_t)(rowbase + tid) * PAD], m);
  }
  __syncthreads();

  for (int i = tid; i < RB * SLOTS; i += 256) {
    const int r = i / SLOTS, j = i - r * SLOTS;
    if ((unsigned)j < lm[r]) {
      const unsigned pos = lbase[r] + (unsigned)j;
      if (pos < CAP) cand[(size_t)(rowbase + r) * CAP + pos] = stash[i];
    }
  }
}

// ---------------- per-row bitonic sort of u64 keys (descending) ----------------
__global__ void k_sort(const unsigned* __restrict__ cnt,
                       const unsigned long long* __restrict__ cand,
                       unsigned* __restrict__ neg) {
  extern __shared__ unsigned long long sk[];
  const int b = blockIdx.x;
  unsigned m = cnt[(size_t)b * PAD];
  if (m > CAP) m = CAP;

  for (int i = threadIdx.x; i < CAP; i += (int)blockDim.x)
    sk[i] = (i < (int)m) ? cand[(size_t)b * CAP + i] : 0ULL;  // 0 sorts last
  __syncthreads();

  for (int k = 2; k <= CAP; k <<= 1) {
    for (int j = k >> 1; j > 0; j >>= 1) {
      for (int i = threadIdx.x; i < CAP / 2; i += (int)blockDim.x) {
        int t = i & (j - 1);
        int p = ((i - t) << 1) + t;
        int q = p + j;
        bool up = ((p & k) == 0);
        unsigned long long a = sk[p], c = sk[q];
        bool sw = up ? (a < c) : (a > c);
        if (sw) { sk[p] = c; sk[q] = a; }
      }
      __syncthreads();
    }
  }

  for (int i = threadIdx.x; i < KK; i += (int)blockDim.x) {
    unsigned idx = 0xFFFFFFFFu - (unsigned)(sk[i] & 0xFFFFFFFFull);
    neg[(size_t)b * KK + i] = (sk[i] == 0ULL) ? 0u : idx;
  }
}

// ---------------- contrast: out = exp(dot/T), block partial sums for Z ----------
__global__ __launch_bounds__(256) void k_contrast(
    const float* __restrict__ anchor, const float* __restrict__ pair,
    const float* __restrict__ bank, const unsigned* __restrict__ neg,
    float* __restrict__ out, double* __restrict__ zpart) {
  __shared__ __align__(16) float As[DD];
  __shared__ double wsum[4];
  const int bid = blockIdx.x;
  double myv;
  if (bid < BB * (KK / 256)) {           // 4096 negative blocks
    const int b = bid >> 4;
    const int k = ((bid & 15) << 8) + threadIdx.x;
    if (threadIdx.x < DD) As[threadIdx.x] = anchor[(size_t)b * DD + threadIdx.x];
    __syncthreads();
    const unsigned idx = neg[(size_t)b * KK + k];
    const float4* __restrict__ rp = (const float4*)(bank + (size_t)idx * DD);
    const float4* __restrict__ apv = (const float4*)As;
    float s = 0.f;
#pragma unroll
    for (int q = 0; q < DD / 4; ++q) {
      float4 rv = rp[q], av = apv[q];
      s = fmaf(rv.x, av.x, s);
      s = fmaf(rv.y, av.y, s);
      s = fmaf(rv.z, av.z, s);
      s = fmaf(rv.w, av.w, s);
    }
    float e = expf(s * (1.0f / 0.07f));
    out[(size_t)b * (KK + 1) + 1 + k] = e;
    myv = (double)e;
  } else {                               // positive slot: out[b][0]
    const int b = threadIdx.x;
    const float* __restrict__ apr = anchor + (size_t)b * DD;
    const float* __restrict__ ppr = pair + (size_t)b * DD;
    float s = 0.f;
#pragma unroll
    for (int q = 0; q < DD; ++q) s = fmaf(apr[q], ppr[q], s);
    float e = expf(s * (1.0f / 0.07f));
    out[(size_t)b * (KK + 1)] = e;
    myv = (double)e;
  }
  for (int off = 32; off > 0; off >>= 1) myv += __shfl_down(myv, off, 64);
  if ((threadIdx.x & 63) == 0) wsum[threadIdx.x >> 6] = myv;
  __syncthreads();
  if (threadIdx.x == 0) zpart[bid] = (wsum[0] + wsum[1]) + (wsum[2] + wsum[3]);
}

// ---------------- Z reduction (deterministic) ----------------
__global__ void k_zreduce(const double* __restrict__ zpart, double* __restrict__ invZ) {
  __shared__ double w[16];
  double v = 0.0;
  for (int i = threadIdx.x; i < BB * (KK / 256) + 1; i += 1024) v += zpart[i];
  for (int off = 32; off > 0; off >>= 1) v += __shfl_down(v, off, 64);
  if ((threadIdx.x & 63) == 0) w[threadIdx.x >> 6] = v;
  __syncthreads();
  if (threadIdx.x == 0) {
    double t = 0.0;
    for (int q = 0; q < 16; ++q) t += w[q];
    double Z = t / ((double)BB * (double)(KK + 1)) * (double)NN;
    invZ[0] = 1.0 / Z;
  }
}

// ---------------- final scale ----------------
__global__ void k_scale(float* __restrict__ out, const double* __restrict__ invZ) {
  double iz = invZ[0];
  int i = blockIdx.x * 512 + threadIdx.x;
  if (i < NOUT) out[i] = (float)((double)out[i] * iz);
}

extern "C" void kernel_launch(void* const* d_in, const int* in_sizes, int n_in,
                              void* d_out, int out_size, void* d_ws, size_t ws_size,
                              hipStream_t stream) {
  const float* anchor = (const float*)d_in[0];
  const float* pair   = (const float*)d_in[1];
  const float* bank   = (const float*)d_in[2];
  const float* thr    = (const float*)d_in[4];
  float* out = (float*)d_out;

  char* w = (char*)d_ws;
  unsigned* cnt = (unsigned*)(w);                                   // 32 KiB (padded)
  unsigned long long* cand = (unsigned long long*)(w + BB * PAD * 4);  // 16 MiB
  unsigned* neg = (unsigned*)(w + BB * PAD * 4 + (size_t)BB * CAP * 8);  // 4 MiB
  double* zpart = (double*)(w + BB * PAD * 4 + (size_t)BB * CAP * 8 + (size_t)BB * KK * 4);
  double* invZ  = (double*)((char*)zpart + (size_t)(BB * (KK / 256) + 1) * 8);

  k_zero<<<1, 256, 0, stream>>>(cnt);
  (void)hipFuncSetAttribute((const void*)k_score<8, 2>,
                            hipFuncAttributeMaxDynamicSharedMemorySize, SMEM(8));
  (void)hipFuncSetAttribute((const void*)k_score<4, 3>,
                            hipFuncAttributeMaxDynamicSharedMemorySize, SMEM(4));
  // A/B: v1 = pk+BK8 (2 blk/CU) on slices [0,128); v2 = pk+BK4 (3 blk/CU) on
  // slices [128,256). Within-probe comparison isolates the occupancy lever.
  k_score<8, 2><<<NRBLK * HSL, 256, SMEM(8), stream>>>(bank, anchor, thr, cnt, cand, 0);
  k_score<4, 3><<<NRBLK * HSL, 256, SMEM(4), stream>>>(bank, anchor, thr, cnt, cand, HSL);
  (void)hipFuncSetAttribute((const void*)k_sort,
                            hipFuncAttributeMaxDynamicSharedMemorySize, CAP * 8);
  k_sort<<<BB, 1024, CAP * 8, stream>>>(cnt, cand, neg);
  k_contrast<<<BB * (KK / 256) + 1, 256, 0, stream>>>(anchor, pair, bank, neg, out, zpart);
  k_zreduce<<<1, 1024, 0, stream>>>(zpart, invZ);
  k_scale<<<(NOUT + 511) / 512, 512, 0, stream>>>(out, invZ);
}

// Round 14
// 445.162 us; speedup vs baseline: 1.1439x; 1.0238x over previous
//
#include <hip/hip_runtime.h>
#include <math.h>

#define BB 256
#define NN 262144
#define DD 128
#define KK 4096
#define CAP 8192
#define NOUT (BB * (KK + 1))
#define THETA0 0.172f

#define RB 16            // rows per block
#define CB 1024          // cols per block
#define NRBLK (BB / RB)  // 16 row-blocks
#define NCSL (NN / CB)   // 256 col-slices
#define HSL (NCSL / 2)   // slices per variant (A/B split)
#define SLOTS 56         // per-row stash slots per block
#define PAD 32           // cnt stride in dwords -> 128 B per counter
// v1 LDS (BK8 + A tile): Bs[2][8][CB] + As[DD][16] + stash + ctrs
#define SMEM1 ((2 * 8 * CB + DD * 16) * 4 + RB * SLOTS * 8 + 3 * RB * 4)
// v2 LDS (BK4, no A tile): Bs[2][4][CB] + stash + ctrs
#define SMEM2 ((2 * 4 * CB) * 4 + RB * SLOTS * 8 + 3 * RB * 4)

typedef float f2 __attribute__((ext_vector_type(2)));
typedef float f16v __attribute__((ext_vector_type(16)));

static __device__ __forceinline__ f2 pkfma(f2 a, f2 b, f2 c) {
  return __builtin_elementwise_fma(a, b, c);
}

// ---------------- zero the per-row candidate counters (padded) ----------------
__global__ __launch_bounds__(256) void k_zero(unsigned* __restrict__ cnt) {
  for (int i = threadIdx.x; i < BB * PAD; i += 256) cnt[i] = 0u;
}

// ---- build At2[rowblk][d][16]: 64B-contiguous A-fragment per (rowblk,d) ----
__global__ __launch_bounds__(256) void k_tr2(const float* __restrict__ anchor,
                                             float* __restrict__ At2) {
  const int i = blockIdx.x * 256 + threadIdx.x;   // 32768
  const int r = i & 15, d = (i >> 4) & (DD - 1), rb = i >> 11;
  At2[i] = anchor[(size_t)(rb * RB + r) * DD + d];
}

// ============ V1 (control = round-13 winner): BK8, A via LDS, pk ============
__global__ __launch_bounds__(256, 2) void k_score_v1(
    const float* __restrict__ bank, const float* __restrict__ anchor,
    const float* __restrict__ thr, unsigned* __restrict__ cnt,
    unsigned long long* __restrict__ cand, int slice_base) {
  extern __shared__ float smem[];
  float* Bs = smem;                                  // [2][8][CB]
  float* As = smem + 2 * 8 * CB;                     // [DD][16]
  unsigned long long* stash =
      (unsigned long long*)(smem + 2 * 8 * CB + DD * 16);
  unsigned* lcnt  = (unsigned*)(stash + RB * SLOTS);
  unsigned* lbase = lcnt + RB;
  unsigned* lm    = lbase + RB;

  const int tid = threadIdx.x;
  const int wave = tid >> 6;
  const int lane = tid & 63;
  const int l = tid & 127;
  const int rh = tid >> 7;
  const int bid = blockIdx.x;
  const int xcd = bid & 7;
  const int u = bid >> 3;
  const int rowblk = u & (NRBLK - 1);
  const int sgrp = u >> 4;
  const int rowbase = rowblk * RB;
  const int cb = (slice_base + sgrp * 8 + xcd) * CB;

  if (tid < RB) lcnt[tid] = 0u;

  for (int i = tid; i < DD * 16; i += 256) {
    const int d = i >> 4, r = i & 15;
    As[d * 16 + r] = anchor[(size_t)(rowbase + r) * DD + d];
  }

#define STAGE1(SLOT, D0)                                                     \
  for (int t = wave; t < 32; t += 4) {                                       \
    const int d = t >> 2, q = t & 3;                                         \
    const float* gsrc =                                                      \
        bank + (size_t)((D0) + d) * NN + cb + q * 256 + lane * 4;            \
    __builtin_amdgcn_global_load_lds(                                        \
        (const __attribute__((address_space(1))) void*)gsrc,                 \
        (__attribute__((address_space(3))) void*)                            \
            &Bs[((size_t)(SLOT)*8 + d) * CB + q * 256],                      \
        16, 0, 0);                                                           \
  }

  STAGE1(0, 0)
  __syncthreads();

  f2 acc2[32];
#pragma unroll
  for (int i = 0; i < 32; ++i) acc2[i] = (f2){0.f, 0.f};

  const float4* __restrict__ As4 = (const float4*)As;

  for (int ch = 0; ch < 16; ++ch) {
    const int cur = ch & 1;
    if (ch + 1 < 16) { STAGE1(cur ^ 1, (ch + 1) * 8) }

    const float* __restrict__ Bc = &Bs[(size_t)cur * 8 * CB];
    const int d0 = ch * 8;
#pragma unroll
    for (int dd = 0; dd < 8; ++dd) {
      const int d = d0 + dd;
      const float4 a0 = As4[d * 4 + rh * 2];
      const float4 a1 = As4[d * 4 + rh * 2 + 1];
      const float4 bx = *(const float4*)&Bc[dd * CB + 4 * l];
      const float4 by = *(const float4*)&Bc[dd * CB + 4 * l + 512];
      const f2 b0 = {bx.x, bx.y}, b1 = {bx.z, bx.w};
      const f2 b2 = {by.x, by.y}, b3 = {by.z, by.w};
#define FMA_ROW(R, AV)                                          \
      {                                                         \
        const f2 av2 = {AV, AV};                                \
        acc2[(R)*4 + 0] = pkfma(av2, b0, acc2[(R)*4 + 0]);      \
        acc2[(R)*4 + 1] = pkfma(av2, b1, acc2[(R)*4 + 1]);      \
        acc2[(R)*4 + 2] = pkfma(av2, b2, acc2[(R)*4 + 2]);      \
        acc2[(R)*4 + 3] = pkfma(av2, b3, acc2[(R)*4 + 3]);      \
      }
      FMA_ROW(0, a0.x) FMA_ROW(1, a0.y) FMA_ROW(2, a0.z) FMA_ROW(3, a0.w)
      FMA_ROW(4, a1.x) FMA_ROW(5, a1.y) FMA_ROW(6, a1.z) FMA_ROW(7, a1.w)
#undef FMA_ROW
    }
    __syncthreads();
  }
#undef STAGE1

  const float tv = thr[0];
#pragma unroll
  for (int r = 0; r < 8; ++r) {
    const int brow = rh * 8 + r;
#pragma unroll
    for (int q = 0; q < 4; ++q) {
      const int colb = cb + (q < 2 ? 4 * l + 2 * q : 512 + 4 * l + 2 * (q - 2));
#pragma unroll
      for (int e = 0; e < 2; ++e) {
        const float s = (e == 0) ? acc2[r * 4 + q].x : acc2[r * 4 + q].y;
        if (s >= THETA0 && s < tv) {
          const unsigned long long key =
              ((unsigned long long)__float_as_uint(s) << 32) |
              (unsigned long long)(0xFFFFFFFFu - (unsigned)(colb + e));
          const unsigned lpos = atomicAdd(&lcnt[brow], 1u);
          if (lpos < SLOTS) {
            stash[brow * SLOTS + lpos] = key;
          } else {
            const unsigned gpos =
                atomicAdd(&cnt[(size_t)(rowbase + brow) * PAD], 1u);
            if (gpos < CAP) cand[(size_t)(rowbase + brow) * CAP + gpos] = key;
          }
        }
      }
    }
  }
  __syncthreads();
  if (tid < RB) {
    const unsigned m = min(lcnt[tid], (unsigned)SLOTS);
    lm[tid] = m;
    lbase[tid] = atomicAdd(&cnt[(size_t)(rowbase + tid) * PAD], m);
  }
  __syncthreads();
  for (int i = tid; i < RB * SLOTS; i += 256) {
    const int r = i / SLOTS, j = i - r * SLOTS;
    if ((unsigned)j < lm[r]) {
      const unsigned pos = lbase[r] + (unsigned)j;
      if (pos < CAP) cand[(size_t)(rowbase + r) * CAP + pos] = stash[i];
    }
  }
}

// ============ V2: 16x4 tile, A in SGPRs via inline-asm s_load ============
// A is block-uniform: force it onto the scalar pipe. Per 2-d sub-chunk:
// 2x s_load_dwordx16 (32 SGPRs) + lgkmcnt(0) + sched_barrier (rule 18).
// LDS per wave-d: ONE ds_read_b128 (B). FMA: v_fmac_f32 v, s, v.
#define LOADA2(VA, VB, PTR)                                              \
  asm volatile("s_load_dwordx16 %0, %2, 0x0\n\t"                         \
               "s_load_dwordx16 %1, %2, 0x40\n\t"                        \
               "s_waitcnt lgkmcnt(0)"                                    \
               : "=&s"(VA), "=&s"(VB)                                    \
               : "s"(PTR));                                              \
  __builtin_amdgcn_sched_barrier(0);

__global__ __launch_bounds__(256, 4) void k_score_v2(
    const float* __restrict__ bank, const float* __restrict__ At2,
    const float* __restrict__ thr, unsigned* __restrict__ cnt,
    unsigned long long* __restrict__ cand, int slice_base) {
  extern __shared__ float smem[];
  float* Bs = smem;                                  // [2][4][CB]
  unsigned long long* stash = (unsigned long long*)(smem + 2 * 4 * CB);
  unsigned* lcnt  = (unsigned*)(stash + RB * SLOTS);
  unsigned* lbase = lcnt + RB;
  unsigned* lm    = lbase + RB;

  const int tid = threadIdx.x;
  const int wave = tid >> 6;
  const int lane = tid & 63;
  const int bid = blockIdx.x;
  const int xcd = bid & 7;
  const int u = bid >> 3;
  const int rowblk = u & (NRBLK - 1);
  const int sgrp = u >> 4;
  const int rowbase = rowblk * RB;
  const int cb = (slice_base + sgrp * 8 + xcd) * CB;

  if (tid < RB) lcnt[tid] = 0u;

  const float* __restrict__ abase = At2 + (size_t)rowblk * DD * 16;

#define STAGE2(SLOT, D0)                                                     \
  for (int t = wave; t < 16; t += 4) {                                       \
    const int d = t >> 2, q = t & 3;                                         \
    const float* gsrc =                                                      \
        bank + (size_t)((D0) + d) * NN + cb + q * 256 + lane * 4;            \
    __builtin_amdgcn_global_load_lds(                                        \
        (const __attribute__((address_space(1))) void*)gsrc,                 \
        (__attribute__((address_space(3))) void*)                            \
            &Bs[((size_t)(SLOT)*4 + d) * CB + q * 256],                      \
        16, 0, 0);                                                           \
  }

  STAGE2(0, 0)
  __syncthreads();   // chunk 0 staged; lcnt visible

  float acc[64];   // [r(16)][c(4)]
#pragma unroll
  for (int i = 0; i < 64; ++i) acc[i] = 0.f;

#define COMP_D(AV, DDI)                                                  \
  {                                                                      \
    const float4 bv = *(const float4*)&Bc[(DDI) * CB + 4 * tid];         \
    _Pragma("unroll") for (int r = 0; r < 16; ++r) {                     \
      acc[r * 4 + 0] = fmaf(AV[r], bv.x, acc[r * 4 + 0]);                \
      acc[r * 4 + 1] = fmaf(AV[r], bv.y, acc[r * 4 + 1]);                \
      acc[r * 4 + 2] = fmaf(AV[r], bv.z, acc[r * 4 + 2]);                \
      acc[r * 4 + 3] = fmaf(AV[r], bv.w, acc[r * 4 + 3]);                \
    }                                                                    \
  }

  for (int ch = 0; ch < 32; ++ch) {
    const int cur = ch & 1;
    if (ch + 1 < 32) { STAGE2(cur ^ 1, (ch + 1) * 4) }

    const float* __restrict__ Bc = &Bs[(size_t)cur * 4 * CB];
    f16v aA, aB, aC, aD;
    LOADA2(aA, aB, abase + ch * 64)           // d = 4ch, 4ch+1 (16 rows each)
    COMP_D(aA, 0)
    COMP_D(aB, 1)
    LOADA2(aC, aD, abase + ch * 64 + 32)      // d = 4ch+2, 4ch+3
    COMP_D(aC, 2)
    COMP_D(aD, 3)
    __syncthreads();
  }
#undef COMP_D
#undef STAGE2

  // ---- two-level threshold append ----
  const float tv = thr[0];
#pragma unroll
  for (int r = 0; r < RB; ++r) {
#pragma unroll
    for (int c = 0; c < 4; ++c) {
      const float s = acc[r * 4 + c];
      if (s >= THETA0 && s < tv) {
        const unsigned col = (unsigned)(cb + tid * 4 + c);
        const unsigned long long key =
            ((unsigned long long)__float_as_uint(s) << 32) |
            (unsigned long long)(0xFFFFFFFFu - col);
        const unsigned lpos = atomicAdd(&lcnt[r], 1u);
        if (lpos < SLOTS) {
          stash[r * SLOTS + lpos] = key;
        } else {
          const unsigned gpos =
              atomicAdd(&cnt[(size_t)(rowbase + r) * PAD], 1u);
          if (gpos < CAP) cand[(size_t)(rowbase + r) * CAP + gpos] = key;
        }
      }
    }
  }
  __syncthreads();
  if (tid < RB) {
    const unsigned m = min(lcnt[tid], (unsigned)SLOTS);
    lm[tid] = m;
    lbase[tid] = atomicAdd(&cnt[(size_t)(rowbase + tid) * PAD], m);
  }
  __syncthreads();
  for (int i = tid; i < RB * SLOTS; i += 256) {
    const int r = i / SLOTS, j = i - r * SLOTS;
    if ((unsigned)j < lm[r]) {
      const unsigned pos = lbase[r] + (unsigned)j;
      if (pos < CAP) cand[(size_t)(rowbase + r) * CAP + pos] = stash[i];
    }
  }
}

// ---------------- per-row bitonic sort of u64 keys (descending) ----------------
__global__ void k_sort(const unsigned* __restrict__ cnt,
                       const unsigned long long* __restrict__ cand,
                       unsigned* __restrict__ neg) {
  extern __shared__ unsigned long long sk[];
  const int b = blockIdx.x;
  unsigned m = cnt[(size_t)b * PAD];
  if (m > CAP) m = CAP;

  for (int i = threadIdx.x; i < CAP; i += (int)blockDim.x)
    sk[i] = (i < (int)m) ? cand[(size_t)b * CAP + i] : 0ULL;
  __syncthreads();

  for (int k = 2; k <= CAP; k <<= 1) {
    for (int j = k >> 1; j > 0; j >>= 1) {
      for (int i = threadIdx.x; i < CAP / 2; i += (int)blockDim.x) {
        int t = i & (j - 1);
        int p = ((i - t) << 1) + t;
        int q = p + j;
        bool up = ((p & k) == 0);
        unsigned long long a = sk[p], c = sk[q];
        bool sw = up ? (a < c) : (a > c);
        if (sw) { sk[p] = c; sk[q] = a; }
      }
      __syncthreads();
    }
  }

  for (int i = threadIdx.x; i < KK; i += (int)blockDim.x) {
    unsigned idx = 0xFFFFFFFFu - (unsigned)(sk[i] & 0xFFFFFFFFull);
    neg[(size_t)b * KK + i] = (sk[i] == 0ULL) ? 0u : idx;
  }
}

// ---------------- contrast: out = exp(dot/T), block partial sums for Z ----------
__global__ __launch_bounds__(256) void k_contrast(
    const float* __restrict__ anchor, const float* __restrict__ pair,
    const float* __restrict__ bank, const unsigned* __restrict__ neg,
    float* __restrict__ out, double* __restrict__ zpart) {
  __shared__ __align__(16) float As[DD];
  __shared__ double wsum[4];
  const int bid = blockIdx.x;
  double myv;
  if (bid < BB * (KK / 256)) {
    const int b = bid >> 4;
    const int k = ((bid & 15) << 8) + threadIdx.x;
    if (threadIdx.x < DD) As[threadIdx.x] = anchor[(size_t)b * DD + threadIdx.x];
    __syncthreads();
    const unsigned idx = neg[(size_t)b * KK + k];
    const float4* __restrict__ rp = (const float4*)(bank + (size_t)idx * DD);
    const float4* __restrict__ apv = (const float4*)As;
    float s = 0.f;
#pragma unroll
    for (int q = 0; q < DD / 4; ++q) {
      float4 rv = rp[q], av = apv[q];
      s = fmaf(rv.x, av.x, s);
      s = fmaf(rv.y, av.y, s);
      s = fmaf(rv.z, av.z, s);
      s = fmaf(rv.w, av.w, s);
    }
    float e = expf(s * (1.0f / 0.07f));
    out[(size_t)b * (KK + 1) + 1 + k] = e;
    myv = (double)e;
  } else {
    const int b = threadIdx.x;
    const float* __restrict__ apr = anchor + (size_t)b * DD;
    const float* __restrict__ ppr = pair + (size_t)b * DD;
    float s = 0.f;
#pragma unroll
    for (int q = 0; q < DD; ++q) s = fmaf(apr[q], ppr[q], s);
    float e = expf(s * (1.0f / 0.07f));
    out[(size_t)b * (KK + 1)] = e;
    myv = (double)e;
  }
  for (int off = 32; off > 0; off >>= 1) myv += __shfl_down(myv, off, 64);
  if ((threadIdx.x & 63) == 0) wsum[threadIdx.x >> 6] = myv;
  __syncthreads();
  if (threadIdx.x == 0) zpart[bid] = (wsum[0] + wsum[1]) + (wsum[2] + wsum[3]);
}

// ---------------- Z reduction (deterministic) ----------------
__global__ void k_zreduce(const double* __restrict__ zpart, double* __restrict__ invZ) {
  __shared__ double w[16];
  double v = 0.0;
  for (int i = threadIdx.x; i < BB * (KK / 256) + 1; i += 1024) v += zpart[i];
  for (int off = 32; off > 0; off >>= 1) v += __shfl_down(v, off, 64);
  if ((threadIdx.x & 63) == 0) w[threadIdx.x >> 6] = v;
  __syncthreads();
  if (threadIdx.x == 0) {
    double t = 0.0;
    for (int q = 0; q < 16; ++q) t += w[q];
    double Z = t / ((double)BB * (double)(KK + 1)) * (double)NN;
    invZ[0] = 1.0 / Z;
  }
}

// ---------------- final scale ----------------
__global__ void k_scale(float* __restrict__ out, const double* __restrict__ invZ) {
  double iz = invZ[0];
  int i = blockIdx.x * 512 + threadIdx.x;
  if (i < NOUT) out[i] = (float)((double)out[i] * iz);
}

extern "C" void kernel_launch(void* const* d_in, const int* in_sizes, int n_in,
                              void* d_out, int out_size, void* d_ws, size_t ws_size,
                              hipStream_t stream) {
  const float* anchor = (const float*)d_in[0];
  const float* pair   = (const float*)d_in[1];
  const float* bank   = (const float*)d_in[2];
  const float* thr    = (const float*)d_in[4];
  float* out = (float*)d_out;

  char* w = (char*)d_ws;
  unsigned* cnt = (unsigned*)(w);                                      // 32 KiB
  unsigned long long* cand = (unsigned long long*)(w + BB * PAD * 4);  // 16 MiB
  unsigned* neg = (unsigned*)(w + BB * PAD * 4 + (size_t)BB * CAP * 8);
  double* zpart = (double*)(w + BB * PAD * 4 + (size_t)BB * CAP * 8 + (size_t)BB * KK * 4);
  double* invZ  = (double*)((char*)zpart + (size_t)(BB * (KK / 256) + 1) * 8);
  float*  At2   = (float*)((char*)invZ + 256);                         // 128 KiB

  k_zero<<<1, 256, 0, stream>>>(cnt);
  k_tr2<<<BB * DD / 256, 256, 0, stream>>>(anchor, At2);
  (void)hipFuncSetAttribute((const void*)k_score_v1,
                            hipFuncAttributeMaxDynamicSharedMemorySize, SMEM1);
  (void)hipFuncSetAttribute((const void*)k_score_v2,
                            hipFuncAttributeMaxDynamicSharedMemorySize, SMEM2);
  // A/B: v1 control on slices [0,128); v2 SGPR-A on slices [128,256)
  k_score_v1<<<NRBLK * HSL, 256, SMEM1, stream>>>(bank, anchor, thr, cnt, cand, 0);
  k_score_v2<<<NRBLK * HSL, 256, SMEM2, stream>>>(bank, At2, thr, cnt, cand, HSL);
  (void)hipFuncSetAttribute((const void*)k_sort,
                            hipFuncAttributeMaxDynamicSharedMemorySize, CAP * 8);
  k_sort<<<BB, 1024, CAP * 8, stream>>>(cnt, cand, neg);
  k_contrast<<<BB * (KK / 256) + 1, 256, 0, stream>>>(anchor, pair, bank, neg, out, zpart);
  k_zreduce<<<1, 1024, 0, stream>>>(zpart, invZ);
  k_scale<<<(NOUT + 511) / 512, 512, 0, stream>>>(out, invZ);
}

// Round 16
// 392.374 us; speedup vs baseline: 1.2978x; 1.1345x over previous
//
#include <hip/hip_runtime.h>
#include <math.h>

#define BB 256
#define NN 262144
#define DD 128
#define KK 4096
#define CAP 8192
#define NOUT (BB * (KK + 1))
#define THETA0 0.172f

#define RB 16            // rows per block
#define CB 1024          // cols per block
#define NRBLK (BB / RB)  // 16 row-blocks
#define NCSL (NN / CB)   // 256 col-slices
#define SLOTS 56         // per-row stash slots per block
#define PAD 32           // cnt stride in dwords -> 128 B per counter
// LDS: Bs[2][4][CB] (32K) + stash (7K) + ctrs -> ~40 KB, 4 blocks/CU
#define SMEMS ((2 * 4 * CB) * 4 + RB * SLOTS * 8 + 3 * RB * 4)

typedef float f16v __attribute__((ext_vector_type(16)));

// ---------------- init: build At2 + zero counters (merged) ----------------
// At2[rowblk][d][16] = anchor[rowblk*16 + r][d]
__global__ __launch_bounds__(256) void k_init(const float* __restrict__ anchor,
                                              float* __restrict__ At2,
                                              unsigned* __restrict__ cnt) {
  const int b = blockIdx.x;
  if (b < NRBLK) {
    for (int j = threadIdx.x; j < DD * 16; j += 256) {
      const int d = j >> 4, r = j & 15;
      At2[(size_t)b * DD * 16 + j] =
          anchor[(size_t)(b * RB + r) * DD + d];
    }
  } else {
    for (int i = threadIdx.x; i < BB * PAD; i += 256) cnt[i] = 0u;
  }
}

// A-fragment load: 2x s_load_dwordx16 + lgkmcnt(0) DRAINED WITHIN ONE ASM.
// r15 lesson: leaving asm s_loads outstanding makes the compiler's counted
// lgkmcnt(N) waits for its own ds_reads unsound (LGKM completes out-of-order
// across types) -> stale B data. Drain atomically; no cross-asm SGPR liveness.
#define LOADA2(VA, VB, PTR, OFF0, OFF1)                                  \
  asm volatile("s_load_dwordx16 %0, %2, " OFF0 "\n\t"                    \
               "s_load_dwordx16 %1, %2, " OFF1 "\n\t"                    \
               "s_waitcnt lgkmcnt(0)"                                    \
               : "=&s"(VA), "=&s"(VB)                                    \
               : "s"(PTR));                                              \
  __builtin_amdgcn_sched_barrier(0);

// ---------------- f32 score GEMM (bit-exact sgemm order) + threshold append ----
// scores[b][n] = sequential f32 FMA over d=0..127 of anchor[b][d]*bank_flat[d*NN+n]
// Barrier-free K-loop: each wave stages exactly the LDS quarter it reads
// (wave w -> cols [256w,256w+256)), so there is NO cross-wave LDS sharing and
// per-wave counted s_waitcnt vmcnt(N) (FIFO vector completion) replaces all
// __syncthreads: 2-slot ring, 2 chunks (8 loads/wave) in flight, vmcnt(4)
// gates the current chunk. A block-uniform in SGPRs via drained LOADA2.
// Per-element accumulation (single acc, d ascending, fmaf) unchanged ->
// ranking bit-identical to the BLAS sgemm reference.
__global__ __launch_bounds__(256, 4) void k_score(
    const float* __restrict__ bank, const float* __restrict__ At2,
    const float* __restrict__ thr, unsigned* __restrict__ cnt,
    unsigned long long* __restrict__ cand) {
  extern __shared__ float smem[];
  float* Bs = smem;                                  // [2][4][CB]
  unsigned long long* stash = (unsigned long long*)(smem + 2 * 4 * CB);
  unsigned* lcnt  = (unsigned*)(stash + RB * SLOTS);
  unsigned* lbase = lcnt + RB;
  unsigned* lm    = lbase + RB;

  const int tid = threadIdx.x;
  const int wave = tid >> 6;
  const int lane = tid & 63;
  const int bid = blockIdx.x;
  const int xcd = bid & 7;
  const int u = bid >> 3;
  const int rowblk = u & (NRBLK - 1);
  const int sgrp = u >> 4;                 // 0..31
  const int rowbase = rowblk * RB;
  const int cb = (sgrp * 8 + xcd) * CB;    // XCD-pinned col-slice

  const float* __restrict__ abase = At2 + (size_t)rowblk * DD * 16;

// stage one chunk (4 d's) into a ring slot: wave w stages quarter q=w of each
// d — exactly the region its own ds_reads consume (cols 4*tid).
#define STAGE(SLOT, D0)                                                      \
  for (int t = wave; t < 16; t += 4) {                                       \
    const int d_ = t >> 2, q_ = t & 3;                                       \
    const float* gsrc =                                                      \
        bank + (size_t)((D0) + d_) * NN + cb + q_ * 256 + lane * 4;          \
    __builtin_amdgcn_global_load_lds(                                        \
        (const __attribute__((address_space(1))) void*)gsrc,                 \
        (__attribute__((address_space(3))) void*)                            \
            &Bs[((size_t)(SLOT)*4 + d_) * CB + q_ * 256],                    \
        16, 0, 0);                                                           \
  }

  STAGE(0, 0)    // chunk 0 -> slot 0  (4 loads/wave in flight)
  STAGE(1, 4)    // chunk 1 -> slot 1  (8 loads/wave in flight)

  const float tv = thr[0];

  float acc[64];   // [r(16)][c(4)], cols = cb + 4*tid + c
#pragma unroll
  for (int i = 0; i < 64; ++i) acc[i] = 0.f;

#define COMP_D(AV, DDI)                                                  \
  {                                                                      \
    const float4 bv = *(const float4*)&Bc[(DDI) * CB + 4 * tid];         \
    _Pragma("unroll") for (int r = 0; r < 16; ++r) {                     \
      acc[r * 4 + 0] = fmaf(AV[r], bv.x, acc[r * 4 + 0]);                \
      acc[r * 4 + 1] = fmaf(AV[r], bv.y, acc[r * 4 + 1]);                \
      acc[r * 4 + 2] = fmaf(AV[r], bv.z, acc[r * 4 + 2]);                \
      acc[r * 4 + 3] = fmaf(AV[r], bv.w, acc[r * 4 + 3]);                \
    }                                                                    \
  }

  for (int ch = 0; ch < 32; ++ch) {
    const float* __restrict__ Bc = &Bs[(size_t)(ch & 1) * 4 * CB];
    const float* pc = abase + ch * 64;

    // gate: this chunk's 4 staging loads (mine, FIFO) have landed
    if (ch < 31) { asm volatile("s_waitcnt vmcnt(4)" ::: "memory"); }
    else         { asm volatile("s_waitcnt vmcnt(0)" ::: "memory"); }
    __builtin_amdgcn_sched_barrier(0);

    f16v aA, aB, aC, aD;
    LOADA2(aA, aB, pc, "0x0", "0x40")     // d = 4ch, 4ch+1
    COMP_D(aA, 0)
    COMP_D(aB, 1)
    LOADA2(aC, aD, pc, "0x80", "0xc0")    // d = 4ch+2, 4ch+3
    COMP_D(aC, 2)
    COMP_D(aD, 3)

    // recycle slot ch&1 with chunk ch+2: my ds_reads must be complete
    if (ch < 30) {
      asm volatile("s_waitcnt lgkmcnt(0)" ::: "memory");
      __builtin_amdgcn_sched_barrier(0);
      STAGE(ch & 1, (ch + 2) * 4)
    }
  }
#undef COMP_D
#undef STAGE

  // ---- two-level threshold append ----
  if (tid < RB) lcnt[tid] = 0u;
  __syncthreads();   // re-converge wave skew; lcnt visible

#pragma unroll
  for (int r = 0; r < RB; ++r) {
#pragma unroll
    for (int c = 0; c < 4; ++c) {
      const float s = acc[r * 4 + c];
      if (s >= THETA0 && s < tv) {
        const unsigned col = (unsigned)(cb + tid * 4 + c);
        // key: desc by f32 score bits (all candidates > 0), tie -> asc idx
        const unsigned long long key =
            ((unsigned long long)__float_as_uint(s) << 32) |
            (unsigned long long)(0xFFFFFFFFu - col);
        const unsigned lpos = atomicAdd(&lcnt[r], 1u);
        if (lpos < SLOTS) {
          stash[r * SLOTS + lpos] = key;
        } else {  // overflow fallback (statistically never; correctness-safe)
          const unsigned gpos = atomicAdd(&cnt[(size_t)(rowbase + r) * PAD], 1u);
          if (gpos < CAP) cand[(size_t)(rowbase + r) * CAP + gpos] = key;
        }
      }
    }
  }
  __syncthreads();

  if (tid < RB) {
    const unsigned m = min(lcnt[tid], (unsigned)SLOTS);
    lm[tid] = m;
    lbase[tid] = atomicAdd(&cnt[(size_t)(rowbase + tid) * PAD], m);
  }
  __syncthreads();

  for (int i = tid; i < RB * SLOTS; i += 256) {
    const int r = i / SLOTS, j = i - r * SLOTS;
    if ((unsigned)j < lm[r]) {
      const unsigned pos = lbase[r] + (unsigned)j;
      if (pos < CAP) cand[(size_t)(rowbase + r) * CAP + pos] = stash[i];
    }
  }
}

// ---------------- per-row bitonic sort of u64 keys (descending) ----------------
__global__ void k_sort(const unsigned* __restrict__ cnt,
                       const unsigned long long* __restrict__ cand,
                       unsigned* __restrict__ neg) {
  extern __shared__ unsigned long long sk[];
  const int b = blockIdx.x;
  unsigned m = cnt[(size_t)b * PAD];
  if (m > CAP) m = CAP;

  for (int i = threadIdx.x; i < CAP; i += (int)blockDim.x)
    sk[i] = (i < (int)m) ? cand[(size_t)b * CAP + i] : 0ULL;  // 0 sorts last
  __syncthreads();

  for (int k = 2; k <= CAP; k <<= 1) {
    for (int j = k >> 1; j > 0; j >>= 1) {
      for (int i = threadIdx.x; i < CAP / 2; i += (int)blockDim.x) {
        int t = i & (j - 1);
        int p = ((i - t) << 1) + t;
        int q = p + j;
        bool up = ((p & k) == 0);
        unsigned long long a = sk[p], c = sk[q];
        bool sw = up ? (a < c) : (a > c);
        if (sw) { sk[p] = c; sk[q] = a; }
      }
      __syncthreads();
    }
  }

  for (int i = threadIdx.x; i < KK; i += (int)blockDim.x) {
    unsigned idx = 0xFFFFFFFFu - (unsigned)(sk[i] & 0xFFFFFFFFull);
    neg[(size_t)b * KK + i] = (sk[i] == 0ULL) ? 0u : idx;
  }
}

// ---------------- contrast: out = exp(dot/T), block partial sums for Z ----------
__global__ __launch_bounds__(256) void k_contrast(
    const float* __restrict__ anchor, const float* __restrict__ pair,
    const float* __restrict__ bank, const unsigned* __restrict__ neg,
    float* __restrict__ out, double* __restrict__ zpart) {
  __shared__ __align__(16) float As[DD];
  __shared__ double wsum[4];
  const int bid = blockIdx.x;
  double myv;
  if (bid < BB * (KK / 256)) {
    const int b = bid >> 4;
    const int k = ((bid & 15) << 8) + threadIdx.x;
    if (threadIdx.x < DD) As[threadIdx.x] = anchor[(size_t)b * DD + threadIdx.x];
    __syncthreads();
    const unsigned idx = neg[(size_t)b * KK + k];
    const float4* __restrict__ rp = (const float4*)(bank + (size_t)idx * DD);
    const float4* __restrict__ apv = (const float4*)As;
    float s = 0.f;
#pragma unroll
    for (int q = 0; q < DD / 4; ++q) {
      float4 rv = rp[q], av = apv[q];
      s = fmaf(rv.x, av.x, s);
      s = fmaf(rv.y, av.y, s);
      s = fmaf(rv.z, av.z, s);
      s = fmaf(rv.w, av.w, s);
    }
    float e = expf(s * (1.0f / 0.07f));
    out[(size_t)b * (KK + 1) + 1 + k] = e;
    myv = (double)e;
  } else {
    const int b = threadIdx.x;
    const float* __restrict__ apr = anchor + (size_t)b * DD;
    const float* __restrict__ ppr = pair + (size_t)b * DD;
    float s = 0.f;
#pragma unroll
    for (int q = 0; q < DD; ++q) s = fmaf(apr[q], ppr[q], s);
    float e = expf(s * (1.0f / 0.07f));
    out[(size_t)b * (KK + 1)] = e;
    myv = (double)e;
  }
  for (int off = 32; off > 0; off >>= 1) myv += __shfl_down(myv, off, 64);
  if ((threadIdx.x & 63) == 0) wsum[threadIdx.x >> 6] = myv;
  __syncthreads();
  if (threadIdx.x == 0) zpart[bid] = (wsum[0] + wsum[1]) + (wsum[2] + wsum[3]);
}

// ---------------- Z reduction (deterministic) ----------------
__global__ void k_zreduce(const double* __restrict__ zpart, double* __restrict__ invZ) {
  __shared__ double w[16];
  double v = 0.0;
  for (int i = threadIdx.x; i < BB * (KK / 256) + 1; i += 1024) v += zpart[i];
  for (int off = 32; off > 0; off >>= 1) v += __shfl_down(v, off, 64);
  if ((threadIdx.x & 63) == 0) w[threadIdx.x >> 6] = v;
  __syncthreads();
  if (threadIdx.x == 0) {
    double t = 0.0;
    for (int q = 0; q < 16; ++q) t += w[q];
    double Z = t / ((double)BB * (double)(KK + 1)) * (double)NN;
    invZ[0] = 1.0 / Z;
  }
}

// ---------------- final scale ----------------
__global__ void k_scale(float* __restrict__ out, const double* __restrict__ invZ) {
  double iz = invZ[0];
  int i = blockIdx.x * 512 + threadIdx.x;
  if (i < NOUT) out[i] = (float)((double)out[i] * iz);
}

extern "C" void kernel_launch(void* const* d_in, const int* in_sizes, int n_in,
                              void* d_out, int out_size, void* d_ws, size_t ws_size,
                              hipStream_t stream) {
  const float* anchor = (const float*)d_in[0];
  const float* pair   = (const float*)d_in[1];
  const float* bank   = (const float*)d_in[2];
  const float* thr    = (const float*)d_in[4];
  float* out = (float*)d_out;

  char* w = (char*)d_ws;
  unsigned* cnt = (unsigned*)(w);                                      // 32 KiB
  unsigned long long* cand = (unsigned long long*)(w + BB * PAD * 4);  // 16 MiB
  unsigned* neg = (unsigned*)(w + BB * PAD * 4 + (size_t)BB * CAP * 8);
  double* zpart = (double*)(w + BB * PAD * 4 + (size_t)BB * CAP * 8 + (size_t)BB * KK * 4);
  double* invZ  = (double*)((char*)zpart + (size_t)(BB * (KK / 256) + 1) * 8);
  float*  At2   = (float*)((char*)invZ + 256);                         // 128 KiB

  k_init<<<NRBLK + 1, 256, 0, stream>>>(anchor, At2, cnt);
  (void)hipFuncSetAttribute((const void*)k_score,
                            hipFuncAttributeMaxDynamicSharedMemorySize, SMEMS);
  k_score<<<NRBLK * NCSL, 256, SMEMS, stream>>>(bank, At2, thr, cnt, cand);
  (void)hipFuncSetAttribute((const void*)k_sort,
                            hipFuncAttributeMaxDynamicSharedMemorySize, CAP * 8);
  k_sort<<<BB, 1024, CAP * 8, stream>>>(cnt, cand, neg);
  k_contrast<<<BB * (KK / 256) + 1, 256, 0, stream>>>(anchor, pair, bank, neg, out, zpart);
  k_zreduce<<<1, 1024, 0, stream>>>(zpart, invZ);
  k_scale<<<(NOUT + 511) / 512, 512, 0, stream>>>(out, invZ);
}

// Round 17
// 389.605 us; speedup vs baseline: 1.3070x; 1.0071x over previous
//
#include <hip/hip_runtime.h>
#include <math.h>

#define BB 256
#define NN 262144
#define DD 128
#define KK 4096
#define CAP 8192
#define NOUT (BB * (KK + 1))
#define THETA0 0.172f

#define RB 16            // rows per block
#define CB 1024          // cols per block
#define NRBLK (BB / RB)  // 16 row-blocks
#define NCSL (NN / CB)   // 256 col-slices
#define SLOTS 56         // per-row stash slots per block
#define PAD 32           // cnt stride in dwords -> 128 B per counter
// LDS: Bs[4][2][CB] (32K, 4-slot ring of 2-d halves) + stash (7K) + ctrs
#define SMEMS ((4 * 2 * CB) * 4 + RB * SLOTS * 8 + 3 * RB * 4)

typedef float f16v __attribute__((ext_vector_type(16)));

// ---------------- init: build At2 + zero counters (merged) ----------------
// At2[rowblk][d][16] = anchor[rowblk*16 + r][d]
__global__ __launch_bounds__(256) void k_init(const float* __restrict__ anchor,
                                              float* __restrict__ At2,
                                              unsigned* __restrict__ cnt) {
  const int b = blockIdx.x;
  if (b < NRBLK) {
    for (int j = threadIdx.x; j < DD * 16; j += 256) {
      const int d = j >> 4, r = j & 15;
      At2[(size_t)b * DD * 16 + j] =
          anchor[(size_t)(b * RB + r) * DD + d];
    }
  } else {
    for (int i = threadIdx.x; i < BB * PAD; i += 256) cnt[i] = 0u;
  }
}

// A-fragment load: 2x s_load_dwordx16 + lgkmcnt(0) DRAINED WITHIN ONE ASM
// (r15 lesson: asm s_loads left outstanding make the compiler's counted
// lgkmcnt(N) ds_read waits unsound — LGKM completes out-of-order across types).
#define LOADA2(VA, VB, PTR)                                              \
  asm volatile("s_load_dwordx16 %0, %2, 0x0\n\t"                         \
               "s_load_dwordx16 %1, %2, 0x40\n\t"                        \
               "s_waitcnt lgkmcnt(0)"                                    \
               : "=&s"(VA), "=&s"(VB)                                    \
               : "s"(PTR));                                              \
  __builtin_amdgcn_sched_barrier(0);

// ---------------- f32 score GEMM (bit-exact sgemm order) + threshold append ----
// scores[b][n] = sequential f32 FMA over d=0..127 of anchor[b][d]*bank_flat[d*NN+n]
// Barrier-free K-loop, 4-SLOT HALF-CHUNK RING (r17): pipeline granularity = 2
// d's; staging for half h issues at end of h-4 => ~900 cyc of compute before
// its vmcnt gate (covers HBM latency; r16's 2-chunk ring left ~1 chunk = 512
// cyc => ~26% stall). Same 32KB LDS, same 4-blocks/CU occupancy, same
// self-staging invariant (wave w stages and reads cols [256w,256w+256)).
// Steady-state 8 loads/wave in flight; gate vmcnt(6); epilogue 4/2/0.
// Per-element accumulation (single acc, d ascending, fmaf) unchanged ->
// ranking bit-identical to the BLAS sgemm reference.
__global__ __launch_bounds__(256, 4) void k_score(
    const float* __restrict__ bank, const float* __restrict__ At2,
    const float* __restrict__ thr, unsigned* __restrict__ cnt,
    unsigned long long* __restrict__ cand) {
  extern __shared__ float smem[];
  float* Bs = smem;                                  // [4][2][CB]
  unsigned long long* stash = (unsigned long long*)(smem + 4 * 2 * CB);
  unsigned* lcnt  = (unsigned*)(stash + RB * SLOTS);
  unsigned* lbase = lcnt + RB;
  unsigned* lm    = lbase + RB;

  const int tid = threadIdx.x;
  const int wave = tid >> 6;
  const int lane = tid & 63;
  const int bid = blockIdx.x;
  const int xcd = bid & 7;
  const int u = bid >> 3;
  const int rowblk = u & (NRBLK - 1);
  const int sgrp = u >> 4;                 // 0..31
  const int rowbase = rowblk * RB;
  const int cb = (sgrp * 8 + xcd) * CB;    // XCD-pinned col-slice

  const float* __restrict__ abase = At2 + (size_t)rowblk * DD * 16;

// stage one HALF-chunk (2 d's) into ring slot: wave w stages quarter q=w of
// each d — exactly the region its own ds_reads consume (cols 4*tid).
#define STAGE(SLOT, D0)                                                      \
  _Pragma("unroll")                                                          \
  for (int d_ = 0; d_ < 2; ++d_) {                                           \
    const float* gsrc =                                                      \
        bank + (size_t)((D0) + d_) * NN + cb + wave * 256 + lane * 4;        \
    __builtin_amdgcn_global_load_lds(                                        \
        (const __attribute__((address_space(1))) void*)gsrc,                 \
        (__attribute__((address_space(3))) void*)                            \
            &Bs[((size_t)(SLOT)*2 + d_) * CB + wave * 256 + lane * 4],       \
        16, 0, 0);                                                           \
  }

  STAGE(0, 0)    // halves 0..3 -> slots 0..3 (8 loads/wave in flight)
  STAGE(1, 2)
  STAGE(2, 4)
  STAGE(3, 6)

  const float tv = thr[0];

  float acc[64];   // [r(16)][c(4)], cols = cb + 4*tid + c
#pragma unroll
  for (int i = 0; i < 64; ++i) acc[i] = 0.f;

#define COMP_D(AV, DDI)                                                  \
  {                                                                      \
    const float4 bv = *(const float4*)&Bc[(DDI) * CB + 4 * tid];         \
    _Pragma("unroll") for (int r = 0; r < 16; ++r) {                     \
      acc[r * 4 + 0] = fmaf(AV[r], bv.x, acc[r * 4 + 0]);                \
      acc[r * 4 + 1] = fmaf(AV[r], bv.y, acc[r * 4 + 1]);                \
      acc[r * 4 + 2] = fmaf(AV[r], bv.z, acc[r * 4 + 2]);                \
      acc[r * 4 + 3] = fmaf(AV[r], bv.w, acc[r * 4 + 3]);                \
    }                                                                    \
  }

  for (int h = 0; h < 64; ++h) {         // half-chunk = d in {2h, 2h+1}
    const float* __restrict__ Bc = &Bs[(size_t)(h & 3) * 2 * CB];

    // gate: this half's 2 staging loads (mine, FIFO vmcnt) have landed
    if (h < 61)      { asm volatile("s_waitcnt vmcnt(6)" ::: "memory"); }
    else if (h == 61){ asm volatile("s_waitcnt vmcnt(4)" ::: "memory"); }
    else if (h == 62){ asm volatile("s_waitcnt vmcnt(2)" ::: "memory"); }
    else             { asm volatile("s_waitcnt vmcnt(0)" ::: "memory"); }
    __builtin_amdgcn_sched_barrier(0);

    f16v aA, aB;
    LOADA2(aA, aB, abase + h * 32)       // A rows for d=2h, 2h+1
    COMP_D(aA, 0)
    COMP_D(aB, 1)

    // recycle slot h&3 with half h+4: my ds_reads on it must be complete
    if (h < 60) {
      asm volatile("s_waitcnt lgkmcnt(0)" ::: "memory");
      __builtin_amdgcn_sched_barrier(0);
      STAGE(h & 3, (h + 4) * 2)
    }
  }
#undef COMP_D
#undef STAGE

  // ---- two-level threshold append ----
  if (tid < RB) lcnt[tid] = 0u;
  __syncthreads();   // re-converge wave skew; lcnt visible

#pragma unroll
  for (int r = 0; r < RB; ++r) {
#pragma unroll
    for (int c = 0; c < 4; ++c) {
      const float s = acc[r * 4 + c];
      if (s >= THETA0 && s < tv) {
        const unsigned col = (unsigned)(cb + tid * 4 + c);
        // key: desc by f32 score bits (all candidates > 0), tie -> asc idx
        const unsigned long long key =
            ((unsigned long long)__float_as_uint(s) << 32) |
            (unsigned long long)(0xFFFFFFFFu - col);
        const unsigned lpos = atomicAdd(&lcnt[r], 1u);
        if (lpos < SLOTS) {
          stash[r * SLOTS + lpos] = key;
        } else {  // overflow fallback (statistically never; correctness-safe)
          const unsigned gpos = atomicAdd(&cnt[(size_t)(rowbase + r) * PAD], 1u);
          if (gpos < CAP) cand[(size_t)(rowbase + r) * CAP + gpos] = key;
        }
      }
    }
  }
  __syncthreads();

  if (tid < RB) {
    const unsigned m = min(lcnt[tid], (unsigned)SLOTS);
    lm[tid] = m;
    lbase[tid] = atomicAdd(&cnt[(size_t)(rowbase + tid) * PAD], m);
  }
  __syncthreads();

  for (int i = tid; i < RB * SLOTS; i += 256) {
    const int r = i / SLOTS, j = i - r * SLOTS;
    if ((unsigned)j < lm[r]) {
      const unsigned pos = lbase[r] + (unsigned)j;
      if (pos < CAP) cand[(size_t)(rowbase + r) * CAP + pos] = stash[i];
    }
  }
}

// ---------------- per-row bitonic sort of u64 keys (descending) ----------------
__global__ void k_sort(const unsigned* __restrict__ cnt,
                       const unsigned long long* __restrict__ cand,
                       unsigned* __restrict__ neg) {
  extern __shared__ unsigned long long sk[];
  const int b = blockIdx.x;
  unsigned m = cnt[(size_t)b * PAD];
  if (m > CAP) m = CAP;

  for (int i = threadIdx.x; i < CAP; i += (int)blockDim.x)
    sk[i] = (i < (int)m) ? cand[(size_t)b * CAP + i] : 0ULL;  // 0 sorts last
  __syncthreads();

  for (int k = 2; k <= CAP; k <<= 1) {
    for (int j = k >> 1; j > 0; j >>= 1) {
      for (int i = threadIdx.x; i < CAP / 2; i += (int)blockDim.x) {
        int t = i & (j - 1);
        int p = ((i - t) << 1) + t;
        int q = p + j;
        bool up = ((p & k) == 0);
        unsigned long long a = sk[p], c = sk[q];
        bool sw = up ? (a < c) : (a > c);
        if (sw) { sk[p] = c; sk[q] = a; }
      }
      __syncthreads();
    }
  }

  for (int i = threadIdx.x; i < KK; i += (int)blockDim.x) {
    unsigned idx = 0xFFFFFFFFu - (unsigned)(sk[i] & 0xFFFFFFFFull);
    neg[(size_t)b * KK + i] = (sk[i] == 0ULL) ? 0u : idx;
  }
}

// ---------------- contrast: out = exp(dot/T), block partial sums for Z ----------
__global__ __launch_bounds__(256) void k_contrast(
    const float* __restrict__ anchor, const float* __restrict__ pair,
    const float* __restrict__ bank, const unsigned* __restrict__ neg,
    float* __restrict__ out, double* __restrict__ zpart) {
  __shared__ __align__(16) float As[DD];
  __shared__ double wsum[4];
  const int bid = blockIdx.x;
  double myv;
  if (bid < BB * (KK / 256)) {
    const int b = bid >> 4;
    const int k = ((bid & 15) << 8) + threadIdx.x;
    if (threadIdx.x < DD) As[threadIdx.x] = anchor[(size_t)b * DD + threadIdx.x];
    __syncthreads();
    const unsigned idx = neg[(size_t)b * KK + k];
    const float4* __restrict__ rp = (const float4*)(bank + (size_t)idx * DD);
    const float4* __restrict__ apv = (const float4*)As;
    float s = 0.f;
#pragma unroll
    for (int q = 0; q < DD / 4; ++q) {
      float4 rv = rp[q], av = apv[q];
      s = fmaf(rv.x, av.x, s);
      s = fmaf(rv.y, av.y, s);
      s = fmaf(rv.z, av.z, s);
      s = fmaf(rv.w, av.w, s);
    }
    float e = expf(s * (1.0f / 0.07f));
    out[(size_t)b * (KK + 1) + 1 + k] = e;
    myv = (double)e;
  } else {
    const int b = threadIdx.x;
    const float* __restrict__ apr = anchor + (size_t)b * DD;
    const float* __restrict__ ppr = pair + (size_t)b * DD;
    float s = 0.f;
#pragma unroll
    for (int q = 0; q < DD; ++q) s = fmaf(apr[q], ppr[q], s);
    float e = expf(s * (1.0f / 0.07f));
    out[(size_t)b * (KK + 1)] = e;
    myv = (double)e;
  }
  for (int off = 32; off > 0; off >>= 1) myv += __shfl_down(myv, off, 64);
  if ((threadIdx.x & 63) == 0) wsum[threadIdx.x >> 6] = myv;
  __syncthreads();
  if (threadIdx.x == 0) zpart[bid] = (wsum[0] + wsum[1]) + (wsum[2] + wsum[3]);
}

// ---------------- Z reduction (deterministic) ----------------
__global__ void k_zreduce(const double* __restrict__ zpart, double* __restrict__ invZ) {
  __shared__ double w[16];
  double v = 0.0;
  for (int i = threadIdx.x; i < BB * (KK / 256) + 1; i += 1024) v += zpart[i];
  for (int off = 32; off > 0; off >>= 1) v += __shfl_down(v, off, 64);
  if ((threadIdx.x & 63) == 0) w[threadIdx.x >> 6] = v;
  __syncthreads();
  if (threadIdx.x == 0) {
    double t = 0.0;
    for (int q = 0; q < 16; ++q) t += w[q];
    double Z = t / ((double)BB * (double)(KK + 1)) * (double)NN;
    invZ[0] = 1.0 / Z;
  }
}

// ---------------- final scale ----------------
__global__ void k_scale(float* __restrict__ out, const double* __restrict__ invZ) {
  double iz = invZ[0];
  int i = blockIdx.x * 512 + threadIdx.x;
  if (i < NOUT) out[i] = (float)((double)out[i] * iz);
}

extern "C" void kernel_launch(void* const* d_in, const int* in_sizes, int n_in,
                              void* d_out, int out_size, void* d_ws, size_t ws_size,
                              hipStream_t stream) {
  const float* anchor = (const float*)d_in[0];
  const float* pair   = (const float*)d_in[1];
  const float* bank   = (const float*)d_in[2];
  const float* thr    = (const float*)d_in[4];
  float* out = (float*)d_out;

  char* w = (char*)d_ws;
  unsigned* cnt = (unsigned*)(w);                                      // 32 KiB
  unsigned long long* cand = (unsigned long long*)(w + BB * PAD * 4);  // 16 MiB
  unsigned* neg = (unsigned*)(w + BB * PAD * 4 + (size_t)BB * CAP * 8);
  double* zpart = (double*)(w + BB * PAD * 4 + (size_t)BB * CAP * 8 + (size_t)BB * KK * 4);
  double* invZ  = (double*)((char*)zpart + (size_t)(BB * (KK / 256) + 1) * 8);
  float*  At2   = (float*)((char*)invZ + 256);                         // 128 KiB

  k_init<<<NRBLK + 1, 256, 0, stream>>>(anchor, At2, cnt);
  (void)hipFuncSetAttribute((const void*)k_score,
                            hipFuncAttributeMaxDynamicSharedMemorySize, SMEMS);
  k_score<<<NRBLK * NCSL, 256, SMEMS, stream>>>(bank, At2, thr, cnt, cand);
  (void)hipFuncSetAttribute((const void*)k_sort,
                            hipFuncAttributeMaxDynamicSharedMemorySize, CAP * 8);
  k_sort<<<BB, 1024, CAP * 8, stream>>>(cnt, cand, neg);
  k_contrast<<<BB * (KK / 256) + 1, 256, 0, stream>>>(anchor, pair, bank, neg, out, zpart);
  k_zreduce<<<1, 1024, 0, stream>>>(zpart, invZ);
  k_scale<<<(NOUT + 511) / 512, 512, 0, stream>>>(out, invZ);
}